// Round 4
// baseline (968.306 us; speedup 1.0000x reference)
//
#include <hip/hip_runtime.h>
#include <hip/hip_bf16.h>
#include <cstddef>
#include <cstdint>

// WindowAttention3D fused kernel for MI355X (gfx950).
// Inputs FLOAT32, output FLOAT32 (model confirmed by round-0..3 evidence).
// One workgroup per window-batch b (1024 blocks, 512 threads = 8 waves).
// Pipeline per block: [regs] x rows (f32->bf16) -> qkv (MFMA, W staged in LDS)
// -> S = q k^T + bias(f32) + mask(f32) -> in-register softmax -> P (LDS) ->
// PV -> O (LDS, bf16) -> proj (MFMA) -> reordered f32 store.
// ws: bf16 W_qkv^T (884,736 B) + bf16 W_proj^T (294,912 B) + f32 padded bias
// table (470,448 B) => ~1.65 MB.

using bf16 = __hip_bfloat16;
typedef short v8s __attribute__((ext_vector_type(8)));
typedef float v4f __attribute__((ext_vector_type(4)));

static constexpr int   NTOK   = 99;
static constexpr int   CDIM   = 384;
static constexpr int   NHEAD  = 12;
static constexpr float SCALEF = 0.17677669529663687f;  // 32^-0.5

// ---- LDS geometry (element strides; row strides multiples of 16B) ----
static constexpr int O_LD  = 392;  // O: 99 rows x 392 (384 used) bf16
static constexpr int QK_LD = 40;   // q,k: 112 rows x 40 (32 used)
static constexpr int VT_LD = 136;  // vT: 32 rows x 136 (128 used, k-padded)
static constexpr int P_LD  = 136;  // P: 112 rows x 136 (128 used, col-padded)
static constexpr int WS_LD = 104;  // wstg: 96 rows x 104 (96 used)

static constexpr int OFF_O = 0;
static constexpr int OFF_Q = OFF_O + 99  * O_LD  * 2;   // 77,616
static constexpr int OFF_K = OFF_Q + 112 * QK_LD * 2;   // 86,576
static constexpr int OFF_V = OFF_K + 112 * QK_LD * 2;   // 95,536
static constexpr int OFF_P = OFF_V + 32  * VT_LD * 2;   // 104,240
static constexpr int OFF_W = OFF_P + 112 * P_LD  * 2;   // 134,704
static constexpr int LDS_TOTAL = OFF_W + 96 * WS_LD * 2; // 154,672 <= 160 KiB

__device__ __forceinline__ v4f mfma16x16x32(v8s a, v8s b, v4f c) {
  return __builtin_amdgcn_mfma_f32_16x16x32_bf16(a, b, c, 0, 0, 0);
}

__device__ __forceinline__ short f2bf(float f) {
  bf16 h = __float2bfloat16(f);
  return *reinterpret_cast<short*>(&h);
}

// ---------------- prep: transpose+cast weights, build padded f32 bias --------
__global__ void prep_kernel(const float* __restrict__ Wqkv, const float* __restrict__ Wproj,
                            const float* __restrict__ rpb,  const int* __restrict__ rpi,
                            bf16* __restrict__ WtQKV, bf16* __restrict__ WtP,
                            float* __restrict__ BIAS)
{
  int idx = blockIdx.x * 256 + threadIdx.x;
  if (idx < 1152 * 384) {                     // WtQKV[c][k] = bf16(Wqkv[k][c])
    int c = idx / 384, k = idx - c * 384;
    WtQKV[idx] = __float2bfloat16(Wqkv[k * 1152 + c]);
  } else if (idx < 1152 * 384 + 384 * 384) {  // WtP[c][k] = bf16(Wproj[k][c])
    int j = idx - 1152 * 384;
    int c = j / 384, k = j - c * 384;
    WtP[j] = __float2bfloat16(Wproj[k * 384 + c]);
  } else if (idx < 1152 * 384 + 384 * 384 + NHEAD * 99 * 99) {
    int j = idx - (1152 * 384 + 384 * 384);   // BIAS[h][n][m], zero-padded row/col 0
    int h = j / (99 * 99), r = j - h * (99 * 99);
    int nn = r / 99, mm = r - nn * 99;
    float v = 0.f;
    if (nn > 0 && mm > 0) {
      int t = rpi[(nn - 1) * 98 + (mm - 1)];
      v = rpb[t * NHEAD + h];
    }
    BIAS[j] = v;
  }
}

// ---------------- fused attention ----------------
__global__ __launch_bounds__(512)
void fused_win_attn(const float* __restrict__ x, const float* __restrict__ mask,
                    const float* __restrict__ bproj, const float* __restrict__ BIAS,
                    const bf16* __restrict__ WtQKV, const bf16* __restrict__ WtP,
                    float* __restrict__ out)
{
  __shared__ __align__(16) char smem[LDS_TOTAL];
  bf16* O_lds  = (bf16*)(smem + OFF_O);
  bf16* q_lds  = (bf16*)(smem + OFF_Q);
  bf16* k_lds  = (bf16*)(smem + OFF_K);
  bf16* vT_lds = (bf16*)(smem + OFF_V);
  bf16* P_lds  = (bf16*)(smem + OFF_P);
  bf16* w_lds  = (bf16*)(smem + OFF_W);

  const int b    = blockIdx.x;
  const int tid  = threadIdx.x;
  const int wave = tid >> 6;
  const int lane = tid & 63;
  const int g    = lane >> 4;   // 0..3
  const int li   = lane & 15;   // 0..15
  const int wi   = b & 63;      // window index for mask

  // Phase A: waves 0..6 hold 16 x-rows each (f32 -> bf16 fragments in regs).
  v8s afr[12];
  if (wave < 7) {
    int arow = 16 * wave + li; if (arow > 98) arow = 98;  // clamp: finite, rows>=99 unused
    const float* xb = x + ((size_t)b * NTOK + arow) * CDIM + g * 8;
    #pragma unroll
    for (int s = 0; s < 12; ++s) {
      v4f x0 = *(const v4f*)(xb + s * 32);
      v4f x1 = *(const v4f*)(xb + s * 32 + 4);
      v8s f;
      #pragma unroll
      for (int j = 0; j < 4; ++j) { f[j] = f2bf(x0[j]); f[j + 4] = f2bf(x1[j]); }
      afr[s] = f;
    }
  }

  for (int h = 0; h < NHEAD; ++h) {
    // ---- B1: q|k|v (112x32 each, rows>=99 garbage-finite) = x @ W-slices ----
    v4f qacc[6];
    #pragma unroll
    for (int t = 0; t < 6; ++t) qacc[t] = (v4f){0.f, 0.f, 0.f, 0.f};

    #pragma unroll
    for (int c4 = 0; c4 < 4; ++c4) {          // k-chunks of 96
      for (int idx = tid; idx < 96 * 12; idx += 512) {   // stage W (96 outcols x 96 k)
        int rr = idx / 12, ch = idx - rr * 12;
        int cg = (rr < 32) ? (h * 32 + rr)
               : (rr < 64) ? (CDIM + h * 32 + rr - 32)
                           : (2 * CDIM + h * 32 + rr - 64);
        *(v8s*)(w_lds + rr * WS_LD + ch * 8) =
            *(const v8s*)(WtQKV + (size_t)cg * CDIM + c4 * 96 + ch * 8);
      }
      __syncthreads();
      if (wave < 7) {
        #pragma unroll
        for (int ss = 0; ss < 3; ++ss) {
          const int s = c4 * 3 + ss;
          #pragma unroll
          for (int t = 0; t < 6; ++t) {
            v8s bw = *(const v8s*)(w_lds + (16 * t + li) * WS_LD + ss * 32 + g * 8);
            qacc[t] = mfma16x16x32(afr[s], bw, qacc[t]);
          }
        }
      }
      __syncthreads();
    }
    // epilogue: q (pre-scaled), k row-major; v transposed for PV B-operand
    if (wave < 7) {
      #pragma unroll
      for (int t = 0; t < 6; ++t) {
        #pragma unroll
        for (int j = 0; j < 4; ++j) {
          int row = 16 * wave + g * 4 + j;
          int col = 16 * (t & 1) + li;
          float v = qacc[t][j];
          if (t < 2)      q_lds[row * QK_LD + col] = __float2bfloat16(v * SCALEF);
          else if (t < 4) k_lds[row * QK_LD + col] = __float2bfloat16(v);
          else            vT_lds[col * VT_LD + row] = __float2bfloat16(v);
        }
      }
    }
    // zero vT k-pad (k=112..127) so PV's zero P cols can't meet NaN garbage
    vT_lds[(tid >> 4) * VT_LD + 112 + (tid & 15)] = __float2bfloat16(0.f);
    __syncthreads();

    // ---- B2+B3: S, softmax, P, PV (wave w owns S/O rows 16w..16w+15) ----
    if (wave < 7) {
      v8s aq = *(const v8s*)(q_lds + (16 * wave + li) * QK_LD + g * 8);
      v4f sacc[7];
      #pragma unroll
      for (int t = 0; t < 7; ++t) {
        v8s bk = *(const v8s*)(k_lds + (16 * t + li) * QK_LD + g * 8);
        v4f z = (v4f){0.f, 0.f, 0.f, 0.f};
        sacc[t] = mfma16x16x32(aq, bk, z);
      }
      // bias + mask + column masking
      #pragma unroll
      for (int t = 0; t < 7; ++t) {
        int col = 16 * t + li;
        #pragma unroll
        for (int j = 0; j < 4; ++j) {
          int row = 16 * wave + g * 4 + j;
          float s = sacc[t][j];
          if (col >= NTOK) s = -1e30f;
          else if (row < NTOK) {
            s += BIAS[(h * NTOK + row) * NTOK + col];
            if (row > 0 && col > 0)
              s += mask[((size_t)wi * 98 + (row - 1)) * 98 + (col - 1)];
          }
          sacc[t][j] = s;
        }
      }
      // softmax per row (row lives in a 16-lane group; reduce with shfl_xor)
      float linv[4];
      #pragma unroll
      for (int j = 0; j < 4; ++j) {
        float m = -1e30f;
        #pragma unroll
        for (int t = 0; t < 7; ++t) m = fmaxf(m, sacc[t][j]);
        m = fmaxf(m, __shfl_xor(m, 1));
        m = fmaxf(m, __shfl_xor(m, 2));
        m = fmaxf(m, __shfl_xor(m, 4));
        m = fmaxf(m, __shfl_xor(m, 8));
        float l = 0.f;
        #pragma unroll
        for (int t = 0; t < 7; ++t) {
          float p = __expf(sacc[t][j] - m);
          sacc[t][j] = p;
          l += p;
        }
        l += __shfl_xor(l, 1);
        l += __shfl_xor(l, 2);
        l += __shfl_xor(l, 4);
        l += __shfl_xor(l, 8);
        linv[j] = 1.f / l;
        int row = 16 * wave + g * 4 + j;
        #pragma unroll
        for (int t = 0; t < 7; ++t)
          P_lds[row * P_LD + 16 * t + li] = __float2bfloat16(sacc[t][j]);
        P_lds[row * P_LD + 112 + li] = __float2bfloat16(0.f);  // zero K-pad cols
      }
      // PV: O rows = P rows (same wave; no cross-wave dependency)
      v4f oacc[2];
      oacc[0] = (v4f){0.f, 0.f, 0.f, 0.f};
      oacc[1] = (v4f){0.f, 0.f, 0.f, 0.f};
      #pragma unroll
      for (int ks = 0; ks < 4; ++ks) {
        v8s ap = *(const v8s*)(P_lds + (16 * wave + li) * P_LD + ks * 32 + g * 8);
        #pragma unroll
        for (int t = 0; t < 2; ++t) {
          v8s bv = *(const v8s*)(vT_lds + (16 * t + li) * VT_LD + ks * 32 + g * 8);
          oacc[t] = mfma16x16x32(ap, bv, oacc[t]);
        }
      }
      #pragma unroll
      for (int t = 0; t < 2; ++t) {
        #pragma unroll
        for (int j = 0; j < 4; ++j) {
          int row = 16 * wave + g * 4 + j;
          if (row < NTOK)
            O_lds[row * O_LD + h * 32 + 16 * t + li] =
                __float2bfloat16(oacc[t][j] * linv[j]);
        }
      }
    }
    __syncthreads();
  }

  // ---- Phase C: proj out_b = O @ Wproj + b, with (out[:,1:], out[:,:1]) split ----
  const size_t OUT2 = (size_t)1024 * 98 * CDIM;
  const int orow_clamped = (16 * wave + li > 98) ? 98 : 16 * wave + li;  // stay in O region
  for (int cc = 0; cc < 4; ++cc) {            // output col chunks of 96
    v4f pacc[6];
    #pragma unroll
    for (int t = 0; t < 6; ++t) pacc[t] = (v4f){0.f, 0.f, 0.f, 0.f};
    for (int c4 = 0; c4 < 4; ++c4) {          // k-chunks of 96
      for (int idx = tid; idx < 96 * 12; idx += 512) {
        int rr = idx / 12, ch = idx - rr * 12;
        *(v8s*)(w_lds + rr * WS_LD + ch * 8) =
            *(const v8s*)(WtP + ((size_t)(cc * 96 + rr)) * CDIM + c4 * 96 + ch * 8);
      }
      __syncthreads();
      if (wave < 7) {
        #pragma unroll
        for (int ss = 0; ss < 3; ++ss) {
          const int s = c4 * 3 + ss;
          v8s ao = *(const v8s*)(O_lds + orow_clamped * O_LD + s * 32 + g * 8);
          #pragma unroll
          for (int t = 0; t < 6; ++t) {
            v8s bw = *(const v8s*)(w_lds + (16 * t + li) * WS_LD + ss * 32 + g * 8);
            pacc[t] = mfma16x16x32(ao, bw, pacc[t]);
          }
        }
      }
      __syncthreads();
    }
    if (wave < 7) {
      #pragma unroll
      for (int t = 0; t < 6; ++t) {
        #pragma unroll
        for (int j = 0; j < 4; ++j) {
          int row = 16 * wave + g * 4 + j;
          if (row < NTOK) {
            int col = cc * 96 + 16 * t + li;
            float v = pacc[t][j] + bproj[col];
            if (row == 0) out[OUT2 + (size_t)b * CDIM + col] = v;
            else          out[((size_t)b * 98 + (row - 1)) * CDIM + col] = v;
          }
        }
      }
    }
  }
}

extern "C" void kernel_launch(void* const* d_in, const int* in_sizes, int n_in,
                              void* d_out, int out_size, void* d_ws, size_t ws_size,
                              hipStream_t stream) {
  const float* x     = (const float*)d_in[0];
  const float* mask  = (const float*)d_in[1];
  const float* Wqkv  = (const float*)d_in[2];
  const float* rpb   = (const float*)d_in[3];
  const float* Wproj = (const float*)d_in[4];
  const float* bproj = (const float*)d_in[5];
  const int*   rpi   = (const int*)d_in[6];

  bf16*  WtQKV = (bf16*)d_ws;                                   // 884,736 B
  bf16*  WtP   = (bf16*)((char*)d_ws + 884736);                 // 294,912 B
  float* BIAS  = (float*)((char*)d_ws + 884736 + 294912);       // 470,448 B

  const int prep_total = 1152 * 384 + 384 * 384 + NHEAD * 99 * 99;
  prep_kernel<<<(prep_total + 255) / 256, 256, 0, stream>>>(
      Wqkv, Wproj, rpb, rpi, WtQKV, WtP, BIAS);
  fused_win_attn<<<1024, 512, 0, stream>>>(
      x, mask, bproj, BIAS, WtQKV, WtP, (float*)d_out);
}

// Round 5
// 886.138 us; speedup vs baseline: 1.0927x; 1.0927x over previous
//
#include <hip/hip_runtime.h>
#include <hip/hip_bf16.h>
#include <cstddef>
#include <cstdint>

// WindowAttention3D for MI355X (gfx950). Inputs f32, output f32.
// Fast path (needs ~80MB ws):
//   prep   : transpose+cast weights to bf16, build padded f32 bias table.
//   k1_attn: per-window fused qkv+attention (MFMA), O -> ws (bf16).
//            LDS 77KB -> 2 blocks/CU (round-4 was 155KB -> 1 block/CU).
//   k2_proj: tiled MFMA GEMM  out = O @ Wproj + bias  with row-0 split.
// Fallback (small ws): round-4 monolithic kernel (proven correct, 968us).

using bf16 = __hip_bfloat16;
typedef short v8s __attribute__((ext_vector_type(8)));
typedef float v4f __attribute__((ext_vector_type(4)));

static constexpr int   NTOK   = 99;
static constexpr int   CDIM   = 384;
static constexpr int   NHEAD  = 12;
static constexpr float SCALEF = 0.17677669529663687f;  // 32^-0.5

__device__ __forceinline__ v4f mfma16x16x32(v8s a, v8s b, v4f c) {
  return __builtin_amdgcn_mfma_f32_16x16x32_bf16(a, b, c, 0, 0, 0);
}
__device__ __forceinline__ short f2bf(float f) {
  bf16 h = __float2bfloat16(f);
  return *reinterpret_cast<short*>(&h);
}

// ---- ws layout ----
static constexpr size_t WT_QKV_OFF = 0;                         // 884,736 B
static constexpr size_t WT_P_OFF   = 884736;                    // 294,912 B
static constexpr size_t BIAS_OFF   = 884736 + 294912;           // 470,448 B
static constexpr size_t O_WS_OFF   = 1650096;
static constexpr size_t O_WS_BYTES = (size_t)101376 * 384 * 2;  // 77,856,768 B
static constexpr size_t WS_NEEDED  = O_WS_OFF + O_WS_BYTES;     // 79,506,864 B

// ---------------- prep: transpose+cast weights, build padded f32 bias --------
__global__ void prep_kernel(const float* __restrict__ Wqkv, const float* __restrict__ Wproj,
                            const float* __restrict__ rpb,  const int* __restrict__ rpi,
                            bf16* __restrict__ WtQKV, bf16* __restrict__ WtP,
                            float* __restrict__ BIAS)
{
  int idx = blockIdx.x * 256 + threadIdx.x;
  if (idx < 1152 * 384) {                     // WtQKV[c][k] = bf16(Wqkv[k][c])
    int c = idx / 384, k = idx - c * 384;
    WtQKV[idx] = __float2bfloat16(Wqkv[k * 1152 + c]);
  } else if (idx < 1152 * 384 + 384 * 384) {  // WtP[c][k] = bf16(Wproj[k][c])
    int j = idx - 1152 * 384;
    int c = j / 384, k = j - c * 384;
    WtP[j] = __float2bfloat16(Wproj[k * 384 + c]);
  } else if (idx < 1152 * 384 + 384 * 384 + NHEAD * 99 * 99) {
    int j = idx - (1152 * 384 + 384 * 384);   // BIAS[h][n][m], zero-padded row/col 0
    int h = j / (99 * 99), r = j - h * (99 * 99);
    int nn = r / 99, mm = r - nn * 99;
    float v = 0.f;
    if (nn > 0 && mm > 0) {
      int t = rpi[(nn - 1) * 98 + (mm - 1)];
      v = rpb[t * NHEAD + h];
    }
    BIAS[j] = v;
  }
}

// ================= K1: fused qkv + attention, O -> ws ========================
static constexpr int QK_LD = 40;   // q,k: 112 rows x 40 (32 used)
static constexpr int VT_LD = 136;  // vT: 32 rows x 136 (128 used, k-padded)
static constexpr int P_LD  = 136;  // P: 112 rows x 136 (128 used, col-padded)
static constexpr int WS_LD = 104;  // wstg: 96 rows x 104 (96 used)

static constexpr int K1_OFF_Q = 0;
static constexpr int K1_OFF_K = K1_OFF_Q + 112 * QK_LD * 2;   //  8,960
static constexpr int K1_OFF_V = K1_OFF_K + 112 * QK_LD * 2;   // 17,920
static constexpr int K1_OFF_P = K1_OFF_V + 32  * VT_LD * 2;   // 26,624
static constexpr int K1_OFF_W = K1_OFF_P + 112 * P_LD  * 2;   // 57,088
static constexpr int K1_LDS   = K1_OFF_W + 96 * WS_LD * 2;    // 77,056 -> 2 blk/CU

__global__ __launch_bounds__(512)
void k1_attn(const float* __restrict__ x, const float* __restrict__ mask,
             const float* __restrict__ BIAS, const bf16* __restrict__ WtQKV,
             bf16* __restrict__ O_ws)
{
  __shared__ __align__(16) char smem[K1_LDS];
  bf16* q_lds  = (bf16*)(smem + K1_OFF_Q);
  bf16* k_lds  = (bf16*)(smem + K1_OFF_K);
  bf16* vT_lds = (bf16*)(smem + K1_OFF_V);
  bf16* P_lds  = (bf16*)(smem + K1_OFF_P);
  bf16* w_lds  = (bf16*)(smem + K1_OFF_W);

  const int b    = blockIdx.x;
  const int tid  = threadIdx.x;
  const int wave = tid >> 6;
  const int lane = tid & 63;
  const int g    = lane >> 4;
  const int li   = lane & 15;
  const int wi   = b & 63;

  // Phase A: waves 0..6 hold 16 x-rows each (f32 -> bf16 fragments in regs).
  v8s afr[12];
  if (wave < 7) {
    int arow = 16 * wave + li; if (arow > 98) arow = 98;
    const float* xb = x + ((size_t)b * NTOK + arow) * CDIM + g * 8;
    #pragma unroll
    for (int s = 0; s < 12; ++s) {
      v4f x0 = *(const v4f*)(xb + s * 32);
      v4f x1 = *(const v4f*)(xb + s * 32 + 4);
      v8s f;
      #pragma unroll
      for (int j = 0; j < 4; ++j) { f[j] = f2bf(x0[j]); f[j + 4] = f2bf(x1[j]); }
      afr[s] = f;
    }
  }

  for (int h = 0; h < NHEAD; ++h) {
    v4f qacc[6];
    #pragma unroll
    for (int t = 0; t < 6; ++t) qacc[t] = (v4f){0.f, 0.f, 0.f, 0.f};

    #pragma unroll
    for (int c4 = 0; c4 < 4; ++c4) {          // k-chunks of 96
      for (int idx = tid; idx < 96 * 12; idx += 512) {
        int rr = idx / 12, ch = idx - rr * 12;
        int cg = (rr < 32) ? (h * 32 + rr)
               : (rr < 64) ? (CDIM + h * 32 + rr - 32)
                           : (2 * CDIM + h * 32 + rr - 64);
        *(v8s*)(w_lds + rr * WS_LD + ch * 8) =
            *(const v8s*)(WtQKV + (size_t)cg * CDIM + c4 * 96 + ch * 8);
      }
      __syncthreads();
      if (wave < 7) {
        #pragma unroll
        for (int ss = 0; ss < 3; ++ss) {
          const int s = c4 * 3 + ss;
          #pragma unroll
          for (int t = 0; t < 6; ++t) {
            v8s bw = *(const v8s*)(w_lds + (16 * t + li) * WS_LD + ss * 32 + g * 8);
            qacc[t] = mfma16x16x32(afr[s], bw, qacc[t]);
          }
        }
      }
      __syncthreads();
    }
    if (wave < 7) {
      #pragma unroll
      for (int t = 0; t < 6; ++t) {
        #pragma unroll
        for (int j = 0; j < 4; ++j) {
          int row = 16 * wave + g * 4 + j;
          int col = 16 * (t & 1) + li;
          float v = qacc[t][j];
          if (t < 2)      q_lds[row * QK_LD + col] = __float2bfloat16(v * SCALEF);
          else if (t < 4) k_lds[row * QK_LD + col] = __float2bfloat16(v);
          else            vT_lds[col * VT_LD + row] = __float2bfloat16(v);
        }
      }
    }
    vT_lds[(tid >> 4) * VT_LD + 112 + (tid & 15)] = __float2bfloat16(0.f);
    __syncthreads();

    if (wave < 7) {
      v8s aq = *(const v8s*)(q_lds + (16 * wave + li) * QK_LD + g * 8);
      v4f sacc[7];
      #pragma unroll
      for (int t = 0; t < 7; ++t) {
        v8s bk = *(const v8s*)(k_lds + (16 * t + li) * QK_LD + g * 8);
        v4f z = (v4f){0.f, 0.f, 0.f, 0.f};
        sacc[t] = mfma16x16x32(aq, bk, z);
      }
      #pragma unroll
      for (int t = 0; t < 7; ++t) {
        int col = 16 * t + li;
        #pragma unroll
        for (int j = 0; j < 4; ++j) {
          int row = 16 * wave + g * 4 + j;
          float s = sacc[t][j];
          if (col >= NTOK) s = -1e30f;
          else if (row < NTOK) {
            s += BIAS[(h * NTOK + row) * NTOK + col];
            if (row > 0 && col > 0)
              s += mask[((size_t)wi * 98 + (row - 1)) * 98 + (col - 1)];
          }
          sacc[t][j] = s;
        }
      }
      float linv[4];
      #pragma unroll
      for (int j = 0; j < 4; ++j) {
        float m = -1e30f;
        #pragma unroll
        for (int t = 0; t < 7; ++t) m = fmaxf(m, sacc[t][j]);
        m = fmaxf(m, __shfl_xor(m, 1));
        m = fmaxf(m, __shfl_xor(m, 2));
        m = fmaxf(m, __shfl_xor(m, 4));
        m = fmaxf(m, __shfl_xor(m, 8));
        float l = 0.f;
        #pragma unroll
        for (int t = 0; t < 7; ++t) {
          float p = __expf(sacc[t][j] - m);
          sacc[t][j] = p;
          l += p;
        }
        l += __shfl_xor(l, 1);
        l += __shfl_xor(l, 2);
        l += __shfl_xor(l, 4);
        l += __shfl_xor(l, 8);
        linv[j] = 1.f / l;
        int row = 16 * wave + g * 4 + j;
        #pragma unroll
        for (int t = 0; t < 7; ++t)
          P_lds[row * P_LD + 16 * t + li] = __float2bfloat16(sacc[t][j]);
        P_lds[row * P_LD + 112 + li] = __float2bfloat16(0.f);
      }
      v4f oacc[2];
      oacc[0] = (v4f){0.f, 0.f, 0.f, 0.f};
      oacc[1] = (v4f){0.f, 0.f, 0.f, 0.f};
      #pragma unroll
      for (int ks = 0; ks < 4; ++ks) {
        v8s ap = *(const v8s*)(P_lds + (16 * wave + li) * P_LD + ks * 32 + g * 8);
        #pragma unroll
        for (int t = 0; t < 2; ++t) {
          v8s bv = *(const v8s*)(vT_lds + (16 * t + li) * VT_LD + ks * 32 + g * 8);
          oacc[t] = mfma16x16x32(ap, bv, oacc[t]);
        }
      }
      #pragma unroll
      for (int t = 0; t < 2; ++t) {
        #pragma unroll
        for (int j = 0; j < 4; ++j) {
          int row = 16 * wave + g * 4 + j;
          if (row < NTOK)
            O_ws[((size_t)b * 99 + row) * CDIM + h * 32 + 16 * t + li] =
                __float2bfloat16(oacc[t][j] * linv[j]);
        }
      }
    }
    __syncthreads();
  }
}

// ================= K2: proj GEMM  out = O_ws @ WtP^T(+b), split store ========
// Tiles: 128 rows x 192 cols, 512 threads (8 waves x 16 rows), K-chunks of 64.
static constexpr int K2_LD   = 72;                       // 64 used + 8 pad
static constexpr int K2_OFFW = 0;                        // W: 192 x 72 bf16
static constexpr int K2_OFFO = 192 * K2_LD * 2;          // 27,648
static constexpr int K2_LDS  = K2_OFFO + 128 * K2_LD * 2;// 46,080 -> 3 blk/CU LDS

__global__ __launch_bounds__(512)
void k2_proj(const bf16* __restrict__ O_ws, const bf16* __restrict__ WtP,
             const float* __restrict__ bproj, float* __restrict__ out)
{
  __shared__ __align__(16) char smem[K2_LDS];
  bf16* W_lds = (bf16*)(smem + K2_OFFW);
  bf16* O_lds = (bf16*)(smem + K2_OFFO);

  const int tid  = threadIdx.x;
  const int wave = tid >> 6;
  const int lane = tid & 63;
  const int g    = lane >> 4;
  const int li   = lane & 15;
  const int R0   = (blockIdx.x >> 1) * 128;        // 792 M-tiles
  const int CN   = (blockIdx.x & 1) * 192;         // 2 N-tiles

  v4f acc[12];
  #pragma unroll
  for (int t = 0; t < 12; ++t) acc[t] = (v4f){0.f, 0.f, 0.f, 0.f};

  for (int kc = 0; kc < 6; ++kc) {                 // K chunks of 64
    const int k0 = kc * 64;
    // stage W: rows = 192 out-cols, 64 k each (WtP is [col][k])
    #pragma unroll
    for (int r = 0; r < 3; ++r) {
      int item = tid + r * 512;                    // < 1536
      int rr = item >> 3, k8 = item & 7;
      *(v8s*)(W_lds + rr * K2_LD + k8 * 8) =
          *(const v8s*)(WtP + (size_t)(CN + rr) * CDIM + k0 + k8 * 8);
    }
    // stage O: 128 rows x 64 k
    #pragma unroll
    for (int r = 0; r < 2; ++r) {
      int item = tid + r * 512;                    // < 1024
      int rr = item >> 3, k8 = item & 7;
      *(v8s*)(O_lds + rr * K2_LD + k8 * 8) =
          *(const v8s*)(O_ws + (size_t)(R0 + rr) * CDIM + k0 + k8 * 8);
    }
    __syncthreads();
    #pragma unroll
    for (int ks = 0; ks < 2; ++ks) {
      v8s ao = *(const v8s*)(O_lds + (16 * wave + li) * K2_LD + ks * 32 + g * 8);
      #pragma unroll
      for (int t = 0; t < 12; ++t) {
        v8s bw = *(const v8s*)(W_lds + (16 * t + li) * K2_LD + ks * 32 + g * 8);
        acc[t] = mfma16x16x32(ao, bw, acc[t]);
      }
    }
    __syncthreads();
  }

  const size_t OUT2 = (size_t)1024 * 98 * CDIM;
  #pragma unroll
  for (int t = 0; t < 12; ++t) {
    int col = CN + 16 * t + li;
    float bb = bproj[col];
    #pragma unroll
    for (int j = 0; j < 4; ++j) {
      int r = R0 + 16 * wave + g * 4 + j;          // < 101376
      int b = r / 99, n = r - b * 99;
      float v = acc[t][j] + bb;
      if (n == 0) out[OUT2 + (size_t)b * CDIM + col] = v;
      else        out[((size_t)b * 98 + (n - 1)) * CDIM + col] = v;
    }
  }
}

// ================= fallback: round-4 monolithic (proven) =====================
static constexpr int M_O_LD = 392;
static constexpr int M_OFF_O = 0;
static constexpr int M_OFF_Q = M_OFF_O + 99  * M_O_LD * 2;
static constexpr int M_OFF_K = M_OFF_Q + 112 * QK_LD * 2;
static constexpr int M_OFF_V = M_OFF_K + 112 * QK_LD * 2;
static constexpr int M_OFF_P = M_OFF_V + 32  * VT_LD * 2;
static constexpr int M_OFF_W = M_OFF_P + 112 * P_LD  * 2;
static constexpr int M_LDS   = M_OFF_W + 96 * WS_LD * 2;

__global__ __launch_bounds__(512)
void fused_mono(const float* __restrict__ x, const float* __restrict__ mask,
                const float* __restrict__ bproj, const float* __restrict__ BIAS,
                const bf16* __restrict__ WtQKV, const bf16* __restrict__ WtP,
                float* __restrict__ out)
{
  __shared__ __align__(16) char smem[M_LDS];
  bf16* O_lds  = (bf16*)(smem + M_OFF_O);
  bf16* q_lds  = (bf16*)(smem + M_OFF_Q);
  bf16* k_lds  = (bf16*)(smem + M_OFF_K);
  bf16* vT_lds = (bf16*)(smem + M_OFF_V);
  bf16* P_lds  = (bf16*)(smem + M_OFF_P);
  bf16* w_lds  = (bf16*)(smem + M_OFF_W);

  const int b    = blockIdx.x;
  const int tid  = threadIdx.x;
  const int wave = tid >> 6;
  const int lane = tid & 63;
  const int g    = lane >> 4;
  const int li   = lane & 15;
  const int wi   = b & 63;

  v8s afr[12];
  if (wave < 7) {
    int arow = 16 * wave + li; if (arow > 98) arow = 98;
    const float* xb = x + ((size_t)b * NTOK + arow) * CDIM + g * 8;
    #pragma unroll
    for (int s = 0; s < 12; ++s) {
      v4f x0 = *(const v4f*)(xb + s * 32);
      v4f x1 = *(const v4f*)(xb + s * 32 + 4);
      v8s f;
      #pragma unroll
      for (int j = 0; j < 4; ++j) { f[j] = f2bf(x0[j]); f[j + 4] = f2bf(x1[j]); }
      afr[s] = f;
    }
  }

  for (int h = 0; h < NHEAD; ++h) {
    v4f qacc[6];
    #pragma unroll
    for (int t = 0; t < 6; ++t) qacc[t] = (v4f){0.f, 0.f, 0.f, 0.f};
    #pragma unroll
    for (int c4 = 0; c4 < 4; ++c4) {
      for (int idx = tid; idx < 96 * 12; idx += 512) {
        int rr = idx / 12, ch = idx - rr * 12;
        int cg = (rr < 32) ? (h * 32 + rr)
               : (rr < 64) ? (CDIM + h * 32 + rr - 32)
                           : (2 * CDIM + h * 32 + rr - 64);
        *(v8s*)(w_lds + rr * WS_LD + ch * 8) =
            *(const v8s*)(WtQKV + (size_t)cg * CDIM + c4 * 96 + ch * 8);
      }
      __syncthreads();
      if (wave < 7) {
        #pragma unroll
        for (int ss = 0; ss < 3; ++ss) {
          const int s = c4 * 3 + ss;
          #pragma unroll
          for (int t = 0; t < 6; ++t) {
            v8s bw = *(const v8s*)(w_lds + (16 * t + li) * WS_LD + ss * 32 + g * 8);
            qacc[t] = mfma16x16x32(afr[s], bw, qacc[t]);
          }
        }
      }
      __syncthreads();
    }
    if (wave < 7) {
      #pragma unroll
      for (int t = 0; t < 6; ++t) {
        #pragma unroll
        for (int j = 0; j < 4; ++j) {
          int row = 16 * wave + g * 4 + j;
          int col = 16 * (t & 1) + li;
          float v = qacc[t][j];
          if (t < 2)      q_lds[row * QK_LD + col] = __float2bfloat16(v * SCALEF);
          else if (t < 4) k_lds[row * QK_LD + col] = __float2bfloat16(v);
          else            vT_lds[col * VT_LD + row] = __float2bfloat16(v);
        }
      }
    }
    vT_lds[(tid >> 4) * VT_LD + 112 + (tid & 15)] = __float2bfloat16(0.f);
    __syncthreads();

    if (wave < 7) {
      v8s aq = *(const v8s*)(q_lds + (16 * wave + li) * QK_LD + g * 8);
      v4f sacc[7];
      #pragma unroll
      for (int t = 0; t < 7; ++t) {
        v8s bk = *(const v8s*)(k_lds + (16 * t + li) * QK_LD + g * 8);
        v4f z = (v4f){0.f, 0.f, 0.f, 0.f};
        sacc[t] = mfma16x16x32(aq, bk, z);
      }
      #pragma unroll
      for (int t = 0; t < 7; ++t) {
        int col = 16 * t + li;
        #pragma unroll
        for (int j = 0; j < 4; ++j) {
          int row = 16 * wave + g * 4 + j;
          float s = sacc[t][j];
          if (col >= NTOK) s = -1e30f;
          else if (row < NTOK) {
            s += BIAS[(h * NTOK + row) * NTOK + col];
            if (row > 0 && col > 0)
              s += mask[((size_t)wi * 98 + (row - 1)) * 98 + (col - 1)];
          }
          sacc[t][j] = s;
        }
      }
      float linv[4];
      #pragma unroll
      for (int j = 0; j < 4; ++j) {
        float m = -1e30f;
        #pragma unroll
        for (int t = 0; t < 7; ++t) m = fmaxf(m, sacc[t][j]);
        m = fmaxf(m, __shfl_xor(m, 1));
        m = fmaxf(m, __shfl_xor(m, 2));
        m = fmaxf(m, __shfl_xor(m, 4));
        m = fmaxf(m, __shfl_xor(m, 8));
        float l = 0.f;
        #pragma unroll
        for (int t = 0; t < 7; ++t) {
          float p = __expf(sacc[t][j] - m);
          sacc[t][j] = p;
          l += p;
        }
        l += __shfl_xor(l, 1);
        l += __shfl_xor(l, 2);
        l += __shfl_xor(l, 4);
        l += __shfl_xor(l, 8);
        linv[j] = 1.f / l;
        int row = 16 * wave + g * 4 + j;
        #pragma unroll
        for (int t = 0; t < 7; ++t)
          P_lds[row * P_LD + 16 * t + li] = __float2bfloat16(sacc[t][j]);
        P_lds[row * P_LD + 112 + li] = __float2bfloat16(0.f);
      }
      v4f oacc[2];
      oacc[0] = (v4f){0.f, 0.f, 0.f, 0.f};
      oacc[1] = (v4f){0.f, 0.f, 0.f, 0.f};
      #pragma unroll
      for (int ks = 0; ks < 4; ++ks) {
        v8s ap = *(const v8s*)(P_lds + (16 * wave + li) * P_LD + ks * 32 + g * 8);
        #pragma unroll
        for (int t = 0; t < 2; ++t) {
          v8s bv = *(const v8s*)(vT_lds + (16 * t + li) * VT_LD + ks * 32 + g * 8);
          oacc[t] = mfma16x16x32(ap, bv, oacc[t]);
        }
      }
      #pragma unroll
      for (int t = 0; t < 2; ++t) {
        #pragma unroll
        for (int j = 0; j < 4; ++j) {
          int row = 16 * wave + g * 4 + j;
          if (row < NTOK)
            O_lds[row * M_O_LD + h * 32 + 16 * t + li] =
                __float2bfloat16(oacc[t][j] * linv[j]);
        }
      }
    }
    __syncthreads();
  }

  const size_t OUT2 = (size_t)1024 * 98 * CDIM;
  const int orow_clamped = (16 * wave + li > 98) ? 98 : 16 * wave + li;
  for (int cc = 0; cc < 4; ++cc) {
    v4f pacc[6];
    #pragma unroll
    for (int t = 0; t < 6; ++t) pacc[t] = (v4f){0.f, 0.f, 0.f, 0.f};
    for (int c4 = 0; c4 < 4; ++c4) {
      for (int idx = tid; idx < 96 * 12; idx += 512) {
        int rr = idx / 12, ch = idx - rr * 12;
        *(v8s*)(w_lds + rr * WS_LD + ch * 8) =
            *(const v8s*)(WtP + ((size_t)(cc * 96 + rr)) * CDIM + c4 * 96 + ch * 8);
      }
      __syncthreads();
      if (wave < 7) {
        #pragma unroll
        for (int ss = 0; ss < 3; ++ss) {
          const int s = c4 * 3 + ss;
          v8s ao = *(const v8s*)(O_lds + orow_clamped * M_O_LD + s * 32 + g * 8);
          #pragma unroll
          for (int t = 0; t < 6; ++t) {
            v8s bw = *(const v8s*)(w_lds + (16 * t + li) * WS_LD + ss * 32 + g * 8);
            pacc[t] = mfma16x16x32(ao, bw, pacc[t]);
          }
        }
      }
      __syncthreads();
    }
    if (wave < 7) {
      #pragma unroll
      for (int t = 0; t < 6; ++t) {
        #pragma unroll
        for (int j = 0; j < 4; ++j) {
          int row = 16 * wave + g * 4 + j;
          if (row < NTOK) {
            int col = cc * 96 + 16 * t + li;
            float v = pacc[t][j] + bproj[col];
            if (row == 0) out[OUT2 + (size_t)b * CDIM + col] = v;
            else          out[((size_t)b * 98 + (row - 1)) * CDIM + col] = v;
          }
        }
      }
    }
  }
}

extern "C" void kernel_launch(void* const* d_in, const int* in_sizes, int n_in,
                              void* d_out, int out_size, void* d_ws, size_t ws_size,
                              hipStream_t stream) {
  const float* x     = (const float*)d_in[0];
  const float* mask  = (const float*)d_in[1];
  const float* Wqkv  = (const float*)d_in[2];
  const float* rpb   = (const float*)d_in[3];
  const float* Wproj = (const float*)d_in[4];
  const float* bproj = (const float*)d_in[5];
  const int*   rpi   = (const int*)d_in[6];

  bf16*  WtQKV = (bf16*)((char*)d_ws + WT_QKV_OFF);
  bf16*  WtP   = (bf16*)((char*)d_ws + WT_P_OFF);
  float* BIAS  = (float*)((char*)d_ws + BIAS_OFF);

  const int prep_total = 1152 * 384 + 384 * 384 + NHEAD * 99 * 99;
  prep_kernel<<<(prep_total + 255) / 256, 256, 0, stream>>>(
      Wqkv, Wproj, rpb, rpi, WtQKV, WtP, BIAS);

  if (ws_size >= WS_NEEDED) {
    bf16* O_ws = (bf16*)((char*)d_ws + O_WS_OFF);
    k1_attn<<<1024, 512, 0, stream>>>(x, mask, BIAS, WtQKV, O_ws);
    k2_proj<<<792 * 2, 512, 0, stream>>>(O_ws, WtP, bproj, (float*)d_out);
  } else {
    fused_mono<<<1024, 512, 0, stream>>>(x, mask, bproj, BIAS, WtQKV, WtP,
                                         (float*)d_out);
  }
}

// Round 6
// 665.026 us; speedup vs baseline: 1.4560x; 1.3325x over previous
//
#include <hip/hip_runtime.h>
#include <hip/hip_bf16.h>
#include <cstddef>
#include <cstdint>

// WindowAttention3D for MI355X (gfx950). Inputs f32, output f32.
// FULL path (ws >= ~265MB):
//   prep_kernel : WtQKV/WtP (bf16 transposed), BIAS, BM = bias+mask fused.
//   k_qkv       : GEMM x@Wqkv -> qkv_ws bf16 (q pre-scaled), k2-style tiles.
//   k_attn      : per-window attention; O written into q-region of qkv_ws.
//   k2_proj     : GEMM O@Wproj + b (O read from qkv_ws, stride 1152).
// MID path (ws >= ~80MB): round-5 proven k1_attn + k2_proj (O_ws stride 384).
// MONO path: round-4 proven monolith.

using bf16 = __hip_bfloat16;
typedef short v8s __attribute__((ext_vector_type(8)));
typedef float v4f __attribute__((ext_vector_type(4)));

static constexpr int   NTOK   = 99;
static constexpr int   CDIM   = 384;
static constexpr int   NHEAD  = 12;
static constexpr float SCALEF = 0.17677669529663687f;  // 32^-0.5

__device__ __forceinline__ v4f mfma16x16x32(v8s a, v8s b, v4f c) {
  return __builtin_amdgcn_mfma_f32_16x16x32_bf16(a, b, c, 0, 0, 0);
}
__device__ __forceinline__ short f2bf(float f) {
  bf16 h = __float2bfloat16(f);
  return *reinterpret_cast<short*>(&h);
}

// ---- ws layout ----
static constexpr size_t WT_QKV_OFF = 0;                          // 884,736
static constexpr size_t WT_P_OFF   = 884736;                     // 294,912
static constexpr size_t BIAS_OFF   = 884736 + 294912;            // 470,448
static constexpr size_t COMMON_END = 1650096;
// MID tier:
static constexpr size_t O_WS_OFF   = COMMON_END;                 // 77,856,768
static constexpr size_t WS_MID     = O_WS_OFF + (size_t)101376 * 384 * 2; // 79,506,864
// FULL tier:
static constexpr size_t BM_OFF     = COMMON_END;                 // 30,090,240
static constexpr size_t QKV_OFF    = BM_OFF + (size_t)64 * NHEAD * NTOK * NTOK * 4; // 31,740,336
static constexpr size_t WS_FULL    = QKV_OFF + (size_t)101376 * 1152 * 2; // 265,310,640

static constexpr int PREP_BASE = 1152 * 384 + 384 * 384 + NHEAD * 99 * 99;
static constexpr int PREP_BM   = 64 * NHEAD * 99 * 99;

// ---------------- prep ----------------
__global__ void prep_kernel(const float* __restrict__ Wqkv, const float* __restrict__ Wproj,
                            const float* __restrict__ rpb,  const int* __restrict__ rpi,
                            const float* __restrict__ mask,
                            bf16* __restrict__ WtQKV, bf16* __restrict__ WtP,
                            float* __restrict__ BIAS, float* __restrict__ BM, int do_bm)
{
  int idx = blockIdx.x * 256 + threadIdx.x;
  if (idx < 1152 * 384) {                     // WtQKV[c][k] = bf16(Wqkv[k][c])
    int c = idx / 384, k = idx - c * 384;
    WtQKV[idx] = __float2bfloat16(Wqkv[k * 1152 + c]);
  } else if (idx < 1152 * 384 + 384 * 384) {  // WtP[c][k] = bf16(Wproj[k][c])
    int j = idx - 1152 * 384;
    int c = j / 384, k = j - c * 384;
    WtP[j] = __float2bfloat16(Wproj[k * 384 + c]);
  } else if (idx < PREP_BASE) {
    int j = idx - (1152 * 384 + 384 * 384);   // BIAS[h][n][m]
    int h = j / (99 * 99), r = j - h * (99 * 99);
    int nn = r / 99, mm = r - nn * 99;
    float v = 0.f;
    if (nn > 0 && mm > 0) v = rpb[rpi[(nn - 1) * 98 + (mm - 1)] * NHEAD + h];
    BIAS[j] = v;
  } else if (do_bm && idx < PREP_BASE + PREP_BM) {
    int j = idx - PREP_BASE;                  // BM[wi][h][n][m] = bias + mask
    int wi = j / (NHEAD * 9801);
    int r2 = j - wi * (NHEAD * 9801);
    int h = r2 / 9801, rr = r2 - h * 9801;
    int nn = rr / 99, mm = rr - nn * 99;
    float v = 0.f;
    if (nn > 0 && mm > 0)
      v = rpb[rpi[(nn - 1) * 98 + (mm - 1)] * NHEAD + h]
        + mask[((size_t)wi * 98 + (nn - 1)) * 98 + (mm - 1)];
    BM[j] = v;
  }
}

// ================= k_qkv: GEMM x @ Wqkv -> qkv_ws (bf16, q pre-scaled) ======
// Tiles 128x192, 512 threads, K-chunks of 64. M=101376, N=1152, K=384.
static constexpr int GQ_LD   = 72;
static constexpr int GQ_OFFB = 0;                          // B: 192 x 72
static constexpr int GQ_OFFA = 192 * GQ_LD * 2;            // 27,648
static constexpr int GQ_LDS  = GQ_OFFA + 128 * GQ_LD * 2;  // 46,080

__global__ __launch_bounds__(512)
void k_qkv(const float* __restrict__ x, const bf16* __restrict__ WtQKV,
           bf16* __restrict__ qkv)
{
  __shared__ __align__(16) char smem[GQ_LDS];
  bf16* B_lds = (bf16*)(smem + GQ_OFFB);
  bf16* A_lds = (bf16*)(smem + GQ_OFFA);

  const int tid  = threadIdx.x;
  const int wave = tid >> 6;
  const int lane = tid & 63;
  const int g    = lane >> 4;
  const int li   = lane & 15;
  const int R0   = (blockIdx.x / 6) * 128;
  const int CN   = (blockIdx.x % 6) * 192;

  v4f acc[12];
  #pragma unroll
  for (int t = 0; t < 12; ++t) acc[t] = (v4f){0.f, 0.f, 0.f, 0.f};

  for (int kc = 0; kc < 6; ++kc) {
    const int k0 = kc * 64;
    // stage B: 192 out-cols x 64 k (WtQKV is [col][k] bf16)
    #pragma unroll
    for (int p = 0; p < 3; ++p) {
      int it = tid + p * 512, rr = it >> 3, k8 = it & 7;
      *(v8s*)(B_lds + rr * GQ_LD + k8 * 8) =
          *(const v8s*)(WtQKV + (size_t)(CN + rr) * 384 + k0 + k8 * 8);
    }
    // stage A: 128 rows x 64 k, f32 -> bf16
    #pragma unroll
    for (int p = 0; p < 2; ++p) {
      int it = tid + p * 512, rr = it >> 3, k8 = it & 7;
      const float* src = x + (size_t)(R0 + rr) * 384 + k0 + k8 * 8;
      v4f x0 = *(const v4f*)(src);
      v4f x1 = *(const v4f*)(src + 4);
      v8s f;
      #pragma unroll
      for (int j = 0; j < 4; ++j) { f[j] = f2bf(x0[j]); f[j + 4] = f2bf(x1[j]); }
      *(v8s*)(A_lds + rr * GQ_LD + k8 * 8) = f;
    }
    __syncthreads();
    #pragma unroll
    for (int ks = 0; ks < 2; ++ks) {
      v8s ao = *(const v8s*)(A_lds + (16 * wave + li) * GQ_LD + ks * 32 + g * 8);
      #pragma unroll
      for (int t = 0; t < 12; ++t) {
        v8s bw = *(const v8s*)(B_lds + (16 * t + li) * GQ_LD + ks * 32 + g * 8);
        acc[t] = mfma16x16x32(ao, bw, acc[t]);
      }
    }
    __syncthreads();
  }

  const float scale = (CN < 384) ? SCALEF : 1.f;   // q block pre-scaled
  #pragma unroll
  for (int t = 0; t < 12; ++t) {
    int col = CN + 16 * t + li;
    #pragma unroll
    for (int j = 0; j < 4; ++j) {
      int r = R0 + 16 * wave + g * 4 + j;
      qkv[(size_t)r * 1152 + col] = __float2bfloat16(acc[t][j] * scale);
    }
  }
}

// ================= k_attn: per-window attention, O -> q-region of qkv_ws ====
static constexpr int A_QK_LD = 40;
static constexpr int A_VT_LD = 104;
static constexpr int A_P_LD  = 104;
static constexpr int A_OFF_Q = 0;
static constexpr int A_OFF_K = A_OFF_Q + 112 * A_QK_LD * 2;  //  8,960
static constexpr int A_OFF_V = A_OFF_K + 112 * A_QK_LD * 2;  // 17,920
static constexpr int A_OFF_P = A_OFF_V + 32  * A_VT_LD * 2;  // 24,576
static constexpr int A_LDS   = A_OFF_P + 112 * A_P_LD  * 2;  // 47,872 -> 3 blk/CU

__global__ __launch_bounds__(448)
void k_attn(const float* __restrict__ BM, bf16* __restrict__ qkv)
{
  __shared__ __align__(16) char smem[A_LDS];
  bf16* q_lds  = (bf16*)(smem + A_OFF_Q);
  bf16* k_lds  = (bf16*)(smem + A_OFF_K);
  bf16* vT_lds = (bf16*)(smem + A_OFF_V);
  bf16* P_lds  = (bf16*)(smem + A_OFF_P);

  const int b    = blockIdx.x;
  const int tid  = threadIdx.x;
  const int wave = tid >> 6;        // 0..6
  const int lane = tid & 63;
  const int g    = lane >> 4;
  const int li   = lane & 15;
  const int wi   = b & 63;

  for (int h = 0; h < NHEAD; ++h) {
    // ---- stage q,k (rows clamped), vT (transposed) for head h ----
    {
      int r = tid >> 2, l4 = tid & 3;              // r: 0..111
      int rc = (r > 98) ? 98 : r;
      const bf16* base = qkv + ((size_t)b * NTOK + rc) * 1152 + h * 32 + l4 * 8;
      *(v8s*)(q_lds + r * A_QK_LD + l4 * 8) = *(const v8s*)(base);
      *(v8s*)(k_lds + r * A_QK_LD + l4 * 8) = *(const v8s*)(base + 384);
      if (r < NTOK) {
        v8s vv = *(const v8s*)(base + 768);
        #pragma unroll
        for (int e = 0; e < 8; ++e)
          *(short*)(vT_lds + (l4 * 8 + e) * A_VT_LD + r) = vv[e];
      }
    }
    __syncthreads();

    // ---- S = q k^T (+BM), softmax, P, PV ----
    {
      v8s aq = *(const v8s*)(q_lds + (16 * wave + li) * A_QK_LD + g * 8);
      v4f sacc[7];
      #pragma unroll
      for (int t = 0; t < 7; ++t) {
        v8s bk = *(const v8s*)(k_lds + (16 * t + li) * A_QK_LD + g * 8);
        v4f z = (v4f){0.f, 0.f, 0.f, 0.f};
        sacc[t] = mfma16x16x32(aq, bk, z);
      }
      const float* bm = BM + (((size_t)wi * NHEAD + h) * NTOK) * NTOK;
      #pragma unroll
      for (int t = 0; t < 7; ++t) {
        int col = 16 * t + li;
        #pragma unroll
        for (int j = 0; j < 4; ++j) {
          int row = 16 * wave + g * 4 + j;
          float s = sacc[t][j];
          if (col >= NTOK) s = -1e30f;
          else if (row < NTOK) s += bm[row * NTOK + col];
          sacc[t][j] = s;
        }
      }
      float linv[4];
      #pragma unroll
      for (int j = 0; j < 4; ++j) {
        float m = -1e30f;
        #pragma unroll
        for (int t = 0; t < 7; ++t) m = fmaxf(m, sacc[t][j]);
        m = fmaxf(m, __shfl_xor(m, 1));
        m = fmaxf(m, __shfl_xor(m, 2));
        m = fmaxf(m, __shfl_xor(m, 4));
        m = fmaxf(m, __shfl_xor(m, 8));
        float l = 0.f;
        #pragma unroll
        for (int t = 0; t < 7; ++t) {
          float p = __expf(sacc[t][j] - m);
          sacc[t][j] = p;
          l += p;
        }
        l += __shfl_xor(l, 1);
        l += __shfl_xor(l, 2);
        l += __shfl_xor(l, 4);
        l += __shfl_xor(l, 8);
        linv[j] = 1.f / l;
        int row = 16 * wave + g * 4 + j;
        #pragma unroll
        for (int t = 0; t < 7; ++t) {
          int col = 16 * t + li;
          if (col < NTOK) P_lds[row * A_P_LD + col] = __float2bfloat16(sacc[t][j]);
        }
      }
      // PV: k-steps 0..2 via MFMA (m 0..95), m=96..98 via VALU tail
      v4f oacc[2];
      oacc[0] = (v4f){0.f, 0.f, 0.f, 0.f};
      oacc[1] = (v4f){0.f, 0.f, 0.f, 0.f};
      #pragma unroll
      for (int ks = 0; ks < 3; ++ks) {
        v8s ap = *(const v8s*)(P_lds + (16 * wave + li) * A_P_LD + ks * 32 + g * 8);
        #pragma unroll
        for (int t = 0; t < 2; ++t) {
          v8s bv = *(const v8s*)(vT_lds + (16 * t + li) * A_VT_LD + ks * 32 + g * 8);
          oacc[t] = mfma16x16x32(ap, bv, oacc[t]);
        }
      }
      #pragma unroll
      for (int t = 0; t < 2; ++t) {
        float v0 = __bfloat162float(vT_lds[(16 * t + li) * A_VT_LD + 96]);
        float v1 = __bfloat162float(vT_lds[(16 * t + li) * A_VT_LD + 97]);
        float v2 = __bfloat162float(vT_lds[(16 * t + li) * A_VT_LD + 98]);
        #pragma unroll
        for (int j = 0; j < 4; ++j) {
          int row = 16 * wave + g * 4 + j;
          float p0 = __bfloat162float(P_lds[row * A_P_LD + 96]);
          float p1 = __bfloat162float(P_lds[row * A_P_LD + 97]);
          float p2 = __bfloat162float(P_lds[row * A_P_LD + 98]);
          oacc[t][j] += p0 * v0 + p1 * v1 + p2 * v2;
        }
      }
      // O into q-region (head h's q is dead after staging)
      #pragma unroll
      for (int t = 0; t < 2; ++t) {
        #pragma unroll
        for (int j = 0; j < 4; ++j) {
          int row = 16 * wave + g * 4 + j;
          if (row < NTOK)
            qkv[((size_t)b * NTOK + row) * 1152 + h * 32 + 16 * t + li] =
                __float2bfloat16(oacc[t][j] * linv[j]);
        }
      }
    }
    __syncthreads();
  }
}

// ================= k2_proj: out = O @ WtP^T + b, split store ================
static constexpr int K2_LD   = 72;
static constexpr int K2_OFFW = 0;
static constexpr int K2_OFFO = 192 * K2_LD * 2;
static constexpr int K2_LDS  = K2_OFFO + 128 * K2_LD * 2;   // 46,080

__global__ __launch_bounds__(512)
void k2_proj(const bf16* __restrict__ O_src, const int o_stride,
             const bf16* __restrict__ WtP, const float* __restrict__ bproj,
             float* __restrict__ out)
{
  __shared__ __align__(16) char smem[K2_LDS];
  bf16* W_lds = (bf16*)(smem + K2_OFFW);
  bf16* O_lds = (bf16*)(smem + K2_OFFO);

  const int tid  = threadIdx.x;
  const int wave = tid >> 6;
  const int lane = tid & 63;
  const int g    = lane >> 4;
  const int li   = lane & 15;
  const int R0   = (blockIdx.x >> 1) * 128;
  const int CN   = (blockIdx.x & 1) * 192;

  v4f acc[12];
  #pragma unroll
  for (int t = 0; t < 12; ++t) acc[t] = (v4f){0.f, 0.f, 0.f, 0.f};

  for (int kc = 0; kc < 6; ++kc) {
    const int k0 = kc * 64;
    #pragma unroll
    for (int p = 0; p < 3; ++p) {
      int it = tid + p * 512, rr = it >> 3, k8 = it & 7;
      *(v8s*)(W_lds + rr * K2_LD + k8 * 8) =
          *(const v8s*)(WtP + (size_t)(CN + rr) * CDIM + k0 + k8 * 8);
    }
    #pragma unroll
    for (int p = 0; p < 2; ++p) {
      int it = tid + p * 512, rr = it >> 3, k8 = it & 7;
      *(v8s*)(O_lds + rr * K2_LD + k8 * 8) =
          *(const v8s*)(O_src + (size_t)(R0 + rr) * o_stride + k0 + k8 * 8);
    }
    __syncthreads();
    #pragma unroll
    for (int ks = 0; ks < 2; ++ks) {
      v8s ao = *(const v8s*)(O_lds + (16 * wave + li) * K2_LD + ks * 32 + g * 8);
      #pragma unroll
      for (int t = 0; t < 12; ++t) {
        v8s bw = *(const v8s*)(W_lds + (16 * t + li) * K2_LD + ks * 32 + g * 8);
        acc[t] = mfma16x16x32(ao, bw, acc[t]);
      }
    }
    __syncthreads();
  }

  const size_t OUT2 = (size_t)1024 * 98 * CDIM;
  #pragma unroll
  for (int t = 0; t < 12; ++t) {
    int col = CN + 16 * t + li;
    float bb = bproj[col];
    #pragma unroll
    for (int j = 0; j < 4; ++j) {
      int r = R0 + 16 * wave + g * 4 + j;
      int b = r / 99, n = r - b * 99;
      float v = acc[t][j] + bb;
      if (n == 0) out[OUT2 + (size_t)b * CDIM + col] = v;
      else        out[((size_t)b * 98 + (n - 1)) * CDIM + col] = v;
    }
  }
}

// ================= MID tier: round-5 proven k1_attn =========================
static constexpr int QK_LD = 40;
static constexpr int VT_LD = 136;
static constexpr int P_LD  = 136;
static constexpr int WS_LD = 104;
static constexpr int K1_OFF_Q = 0;
static constexpr int K1_OFF_K = K1_OFF_Q + 112 * QK_LD * 2;
static constexpr int K1_OFF_V = K1_OFF_K + 112 * QK_LD * 2;
static constexpr int K1_OFF_P = K1_OFF_V + 32  * VT_LD * 2;
static constexpr int K1_OFF_W = K1_OFF_P + 112 * P_LD  * 2;
static constexpr int K1_LDS   = K1_OFF_W + 96 * WS_LD * 2;

__global__ __launch_bounds__(512)
void k1_attn(const float* __restrict__ x, const float* __restrict__ mask,
             const float* __restrict__ BIAS, const bf16* __restrict__ WtQKV,
             bf16* __restrict__ O_ws)
{
  __shared__ __align__(16) char smem[K1_LDS];
  bf16* q_lds  = (bf16*)(smem + K1_OFF_Q);
  bf16* k_lds  = (bf16*)(smem + K1_OFF_K);
  bf16* vT_lds = (bf16*)(smem + K1_OFF_V);
  bf16* P_lds  = (bf16*)(smem + K1_OFF_P);
  bf16* w_lds  = (bf16*)(smem + K1_OFF_W);

  const int b    = blockIdx.x;
  const int tid  = threadIdx.x;
  const int wave = tid >> 6;
  const int lane = tid & 63;
  const int g    = lane >> 4;
  const int li   = lane & 15;
  const int wi   = b & 63;

  v8s afr[12];
  if (wave < 7) {
    int arow = 16 * wave + li; if (arow > 98) arow = 98;
    const float* xb = x + ((size_t)b * NTOK + arow) * CDIM + g * 8;
    #pragma unroll
    for (int s = 0; s < 12; ++s) {
      v4f x0 = *(const v4f*)(xb + s * 32);
      v4f x1 = *(const v4f*)(xb + s * 32 + 4);
      v8s f;
      #pragma unroll
      for (int j = 0; j < 4; ++j) { f[j] = f2bf(x0[j]); f[j + 4] = f2bf(x1[j]); }
      afr[s] = f;
    }
  }

  for (int h = 0; h < NHEAD; ++h) {
    v4f qacc[6];
    #pragma unroll
    for (int t = 0; t < 6; ++t) qacc[t] = (v4f){0.f, 0.f, 0.f, 0.f};
    #pragma unroll
    for (int c4 = 0; c4 < 4; ++c4) {
      for (int idx = tid; idx < 96 * 12; idx += 512) {
        int rr = idx / 12, ch = idx - rr * 12;
        int cg = (rr < 32) ? (h * 32 + rr)
               : (rr < 64) ? (CDIM + h * 32 + rr - 32)
                           : (2 * CDIM + h * 32 + rr - 64);
        *(v8s*)(w_lds + rr * WS_LD + ch * 8) =
            *(const v8s*)(WtQKV + (size_t)cg * CDIM + c4 * 96 + ch * 8);
      }
      __syncthreads();
      if (wave < 7) {
        #pragma unroll
        for (int ss = 0; ss < 3; ++ss) {
          const int s = c4 * 3 + ss;
          #pragma unroll
          for (int t = 0; t < 6; ++t) {
            v8s bw = *(const v8s*)(w_lds + (16 * t + li) * WS_LD + ss * 32 + g * 8);
            qacc[t] = mfma16x16x32(afr[s], bw, qacc[t]);
          }
        }
      }
      __syncthreads();
    }
    if (wave < 7) {
      #pragma unroll
      for (int t = 0; t < 6; ++t) {
        #pragma unroll
        for (int j = 0; j < 4; ++j) {
          int row = 16 * wave + g * 4 + j;
          int col = 16 * (t & 1) + li;
          float v = qacc[t][j];
          if (t < 2)      q_lds[row * QK_LD + col] = __float2bfloat16(v * SCALEF);
          else if (t < 4) k_lds[row * QK_LD + col] = __float2bfloat16(v);
          else            vT_lds[col * VT_LD + row] = __float2bfloat16(v);
        }
      }
    }
    vT_lds[(tid >> 4) * VT_LD + 112 + (tid & 15)] = __float2bfloat16(0.f);
    __syncthreads();

    if (wave < 7) {
      v8s aq = *(const v8s*)(q_lds + (16 * wave + li) * QK_LD + g * 8);
      v4f sacc[7];
      #pragma unroll
      for (int t = 0; t < 7; ++t) {
        v8s bk = *(const v8s*)(k_lds + (16 * t + li) * QK_LD + g * 8);
        v4f z = (v4f){0.f, 0.f, 0.f, 0.f};
        sacc[t] = mfma16x16x32(aq, bk, z);
      }
      #pragma unroll
      for (int t = 0; t < 7; ++t) {
        int col = 16 * t + li;
        #pragma unroll
        for (int j = 0; j < 4; ++j) {
          int row = 16 * wave + g * 4 + j;
          float s = sacc[t][j];
          if (col >= NTOK) s = -1e30f;
          else if (row < NTOK) {
            s += BIAS[(h * NTOK + row) * NTOK + col];
            if (row > 0 && col > 0)
              s += mask[((size_t)wi * 98 + (row - 1)) * 98 + (col - 1)];
          }
          sacc[t][j] = s;
        }
      }
      float linv[4];
      #pragma unroll
      for (int j = 0; j < 4; ++j) {
        float m = -1e30f;
        #pragma unroll
        for (int t = 0; t < 7; ++t) m = fmaxf(m, sacc[t][j]);
        m = fmaxf(m, __shfl_xor(m, 1));
        m = fmaxf(m, __shfl_xor(m, 2));
        m = fmaxf(m, __shfl_xor(m, 4));
        m = fmaxf(m, __shfl_xor(m, 8));
        float l = 0.f;
        #pragma unroll
        for (int t = 0; t < 7; ++t) {
          float p = __expf(sacc[t][j] - m);
          sacc[t][j] = p;
          l += p;
        }
        l += __shfl_xor(l, 1);
        l += __shfl_xor(l, 2);
        l += __shfl_xor(l, 4);
        l += __shfl_xor(l, 8);
        linv[j] = 1.f / l;
        int row = 16 * wave + g * 4 + j;
        #pragma unroll
        for (int t = 0; t < 7; ++t)
          P_lds[row * P_LD + 16 * t + li] = __float2bfloat16(sacc[t][j]);
        P_lds[row * P_LD + 112 + li] = __float2bfloat16(0.f);
      }
      v4f oacc[2];
      oacc[0] = (v4f){0.f, 0.f, 0.f, 0.f};
      oacc[1] = (v4f){0.f, 0.f, 0.f, 0.f};
      #pragma unroll
      for (int ks = 0; ks < 4; ++ks) {
        v8s ap = *(const v8s*)(P_lds + (16 * wave + li) * P_LD + ks * 32 + g * 8);
        #pragma unroll
        for (int t = 0; t < 2; ++t) {
          v8s bv = *(const v8s*)(vT_lds + (16 * t + li) * VT_LD + ks * 32 + g * 8);
          oacc[t] = mfma16x16x32(ap, bv, oacc[t]);
        }
      }
      #pragma unroll
      for (int t = 0; t < 2; ++t) {
        #pragma unroll
        for (int j = 0; j < 4; ++j) {
          int row = 16 * wave + g * 4 + j;
          if (row < NTOK)
            O_ws[((size_t)b * 99 + row) * CDIM + h * 32 + 16 * t + li] =
                __float2bfloat16(oacc[t][j] * linv[j]);
        }
      }
    }
    __syncthreads();
  }
}

// ================= MONO tier: round-4 proven =================================
static constexpr int M_O_LD = 392;
static constexpr int M_OFF_O = 0;
static constexpr int M_OFF_Q = M_OFF_O + 99  * M_O_LD * 2;
static constexpr int M_OFF_K = M_OFF_Q + 112 * QK_LD * 2;
static constexpr int M_OFF_V = M_OFF_K + 112 * QK_LD * 2;
static constexpr int M_OFF_P = M_OFF_V + 32  * VT_LD * 2;
static constexpr int M_OFF_W = M_OFF_P + 112 * P_LD  * 2;
static constexpr int M_LDS   = M_OFF_W + 96 * WS_LD * 2;

__global__ __launch_bounds__(512)
void fused_mono(const float* __restrict__ x, const float* __restrict__ mask,
                const float* __restrict__ bproj, const float* __restrict__ BIAS,
                const bf16* __restrict__ WtQKV, const bf16* __restrict__ WtP,
                float* __restrict__ out)
{
  __shared__ __align__(16) char smem[M_LDS];
  bf16* O_lds  = (bf16*)(smem + M_OFF_O);
  bf16* q_lds  = (bf16*)(smem + M_OFF_Q);
  bf16* k_lds  = (bf16*)(smem + M_OFF_K);
  bf16* vT_lds = (bf16*)(smem + M_OFF_V);
  bf16* P_lds  = (bf16*)(smem + M_OFF_P);
  bf16* w_lds  = (bf16*)(smem + M_OFF_W);

  const int b    = blockIdx.x;
  const int tid  = threadIdx.x;
  const int wave = tid >> 6;
  const int lane = tid & 63;
  const int g    = lane >> 4;
  const int li   = lane & 15;
  const int wi   = b & 63;

  v8s afr[12];
  if (wave < 7) {
    int arow = 16 * wave + li; if (arow > 98) arow = 98;
    const float* xb = x + ((size_t)b * NTOK + arow) * CDIM + g * 8;
    #pragma unroll
    for (int s = 0; s < 12; ++s) {
      v4f x0 = *(const v4f*)(xb + s * 32);
      v4f x1 = *(const v4f*)(xb + s * 32 + 4);
      v8s f;
      #pragma unroll
      for (int j = 0; j < 4; ++j) { f[j] = f2bf(x0[j]); f[j + 4] = f2bf(x1[j]); }
      afr[s] = f;
    }
  }

  for (int h = 0; h < NHEAD; ++h) {
    v4f qacc[6];
    #pragma unroll
    for (int t = 0; t < 6; ++t) qacc[t] = (v4f){0.f, 0.f, 0.f, 0.f};
    #pragma unroll
    for (int c4 = 0; c4 < 4; ++c4) {
      for (int idx = tid; idx < 96 * 12; idx += 512) {
        int rr = idx / 12, ch = idx - rr * 12;
        int cg = (rr < 32) ? (h * 32 + rr)
               : (rr < 64) ? (CDIM + h * 32 + rr - 32)
                           : (2 * CDIM + h * 32 + rr - 64);
        *(v8s*)(w_lds + rr * WS_LD + ch * 8) =
            *(const v8s*)(WtQKV + (size_t)cg * CDIM + c4 * 96 + ch * 8);
      }
      __syncthreads();
      if (wave < 7) {
        #pragma unroll
        for (int ss = 0; ss < 3; ++ss) {
          const int s = c4 * 3 + ss;
          #pragma unroll
          for (int t = 0; t < 6; ++t) {
            v8s bw = *(const v8s*)(w_lds + (16 * t + li) * WS_LD + ss * 32 + g * 8);
            qacc[t] = mfma16x16x32(afr[s], bw, qacc[t]);
          }
        }
      }
      __syncthreads();
    }
    if (wave < 7) {
      #pragma unroll
      for (int t = 0; t < 6; ++t) {
        #pragma unroll
        for (int j = 0; j < 4; ++j) {
          int row = 16 * wave + g * 4 + j;
          int col = 16 * (t & 1) + li;
          float v = qacc[t][j];
          if (t < 2)      q_lds[row * QK_LD + col] = __float2bfloat16(v * SCALEF);
          else if (t < 4) k_lds[row * QK_LD + col] = __float2bfloat16(v);
          else            vT_lds[col * VT_LD + row] = __float2bfloat16(v);
        }
      }
    }
    vT_lds[(tid >> 4) * VT_LD + 112 + (tid & 15)] = __float2bfloat16(0.f);
    __syncthreads();

    if (wave < 7) {
      v8s aq = *(const v8s*)(q_lds + (16 * wave + li) * QK_LD + g * 8);
      v4f sacc[7];
      #pragma unroll
      for (int t = 0; t < 7; ++t) {
        v8s bk = *(const v8s*)(k_lds + (16 * t + li) * QK_LD + g * 8);
        v4f z = (v4f){0.f, 0.f, 0.f, 0.f};
        sacc[t] = mfma16x16x32(aq, bk, z);
      }
      #pragma unroll
      for (int t = 0; t < 7; ++t) {
        int col = 16 * t + li;
        #pragma unroll
        for (int j = 0; j < 4; ++j) {
          int row = 16 * wave + g * 4 + j;
          float s = sacc[t][j];
          if (col >= NTOK) s = -1e30f;
          else if (row < NTOK) {
            s += BIAS[(h * NTOK + row) * NTOK + col];
            if (row > 0 && col > 0)
              s += mask[((size_t)wi * 98 + (row - 1)) * 98 + (col - 1)];
          }
          sacc[t][j] = s;
        }
      }
      float linv[4];
      #pragma unroll
      for (int j = 0; j < 4; ++j) {
        float m = -1e30f;
        #pragma unroll
        for (int t = 0; t < 7; ++t) m = fmaxf(m, sacc[t][j]);
        m = fmaxf(m, __shfl_xor(m, 1));
        m = fmaxf(m, __shfl_xor(m, 2));
        m = fmaxf(m, __shfl_xor(m, 4));
        m = fmaxf(m, __shfl_xor(m, 8));
        float l = 0.f;
        #pragma unroll
        for (int t = 0; t < 7; ++t) {
          float p = __expf(sacc[t][j] - m);
          sacc[t][j] = p;
          l += p;
        }
        l += __shfl_xor(l, 1);
        l += __shfl_xor(l, 2);
        l += __shfl_xor(l, 4);
        l += __shfl_xor(l, 8);
        linv[j] = 1.f / l;
        int row = 16 * wave + g * 4 + j;
        #pragma unroll
        for (int t = 0; t < 7; ++t)
          P_lds[row * P_LD + 16 * t + li] = __float2bfloat16(sacc[t][j]);
        P_lds[row * P_LD + 112 + li] = __float2bfloat16(0.f);
      }
      v4f oacc[2];
      oacc[0] = (v4f){0.f, 0.f, 0.f, 0.f};
      oacc[1] = (v4f){0.f, 0.f, 0.f, 0.f};
      #pragma unroll
      for (int ks = 0; ks < 4; ++ks) {
        v8s ap = *(const v8s*)(P_lds + (16 * wave + li) * P_LD + ks * 32 + g * 8);
        #pragma unroll
        for (int t = 0; t < 2; ++t) {
          v8s bv = *(const v8s*)(vT_lds + (16 * t + li) * VT_LD + ks * 32 + g * 8);
          oacc[t] = mfma16x16x32(ap, bv, oacc[t]);
        }
      }
      #pragma unroll
      for (int t = 0; t < 2; ++t) {
        #pragma unroll
        for (int j = 0; j < 4; ++j) {
          int row = 16 * wave + g * 4 + j;
          if (row < NTOK)
            O_lds[row * M_O_LD + h * 32 + 16 * t + li] =
                __float2bfloat16(oacc[t][j] * linv[j]);
        }
      }
    }
    __syncthreads();
  }

  const size_t OUT2 = (size_t)1024 * 98 * CDIM;
  const int orow_clamped = (16 * wave + li > 98) ? 98 : 16 * wave + li;
  for (int cc = 0; cc < 4; ++cc) {
    v4f pacc[6];
    #pragma unroll
    for (int t = 0; t < 6; ++t) pacc[t] = (v4f){0.f, 0.f, 0.f, 0.f};
    for (int c4 = 0; c4 < 4; ++c4) {
      for (int idx = tid; idx < 96 * 12; idx += 512) {
        int rr = idx / 12, ch = idx - rr * 12;
        *(v8s*)(w_lds + rr * WS_LD + ch * 8) =
            *(const v8s*)(WtP + ((size_t)(cc * 96 + rr)) * CDIM + c4 * 96 + ch * 8);
      }
      __syncthreads();
      if (wave < 7) {
        #pragma unroll
        for (int ss = 0; ss < 3; ++ss) {
          const int s = c4 * 3 + ss;
          v8s ao = *(const v8s*)(O_lds + orow_clamped * M_O_LD + s * 32 + g * 8);
          #pragma unroll
          for (int t = 0; t < 6; ++t) {
            v8s bw = *(const v8s*)(w_lds + (16 * t + li) * WS_LD + ss * 32 + g * 8);
            pacc[t] = mfma16x16x32(ao, bw, pacc[t]);
          }
        }
      }
      __syncthreads();
    }
    if (wave < 7) {
      #pragma unroll
      for (int t = 0; t < 6; ++t) {
        #pragma unroll
        for (int j = 0; j < 4; ++j) {
          int row = 16 * wave + g * 4 + j;
          if (row < NTOK) {
            int col = cc * 96 + 16 * t + li;
            float v = pacc[t][j] + bproj[col];
            if (row == 0) out[OUT2 + (size_t)b * CDIM + col] = v;
            else          out[((size_t)b * 98 + (row - 1)) * CDIM + col] = v;
          }
        }
      }
    }
  }
}

extern "C" void kernel_launch(void* const* d_in, const int* in_sizes, int n_in,
                              void* d_out, int out_size, void* d_ws, size_t ws_size,
                              hipStream_t stream) {
  const float* x     = (const float*)d_in[0];
  const float* mask  = (const float*)d_in[1];
  const float* Wqkv  = (const float*)d_in[2];
  const float* rpb   = (const float*)d_in[3];
  const float* Wproj = (const float*)d_in[4];
  const float* bproj = (const float*)d_in[5];
  const int*   rpi   = (const int*)d_in[6];

  bf16*  WtQKV = (bf16*)((char*)d_ws + WT_QKV_OFF);
  bf16*  WtP   = (bf16*)((char*)d_ws + WT_P_OFF);
  float* BIAS  = (float*)((char*)d_ws + BIAS_OFF);

  const bool full = (ws_size >= WS_FULL);
  const int prep_items = full ? (PREP_BASE + PREP_BM) : PREP_BASE;
  float* BM = (float*)((char*)d_ws + BM_OFF);
  prep_kernel<<<(prep_items + 255) / 256, 256, 0, stream>>>(
      Wqkv, Wproj, rpb, rpi, mask, WtQKV, WtP, BIAS, BM, full ? 1 : 0);

  if (full) {
    bf16* qkv = (bf16*)((char*)d_ws + QKV_OFF);
    k_qkv<<<792 * 6, 512, 0, stream>>>(x, WtQKV, qkv);
    k_attn<<<1024, 448, 0, stream>>>(BM, qkv);
    k2_proj<<<792 * 2, 512, 0, stream>>>(qkv, 1152, WtP, bproj, (float*)d_out);
  } else if (ws_size >= WS_MID) {
    bf16* O_ws = (bf16*)((char*)d_ws + O_WS_OFF);
    k1_attn<<<1024, 512, 0, stream>>>(x, mask, BIAS, WtQKV, O_ws);
    k2_proj<<<792 * 2, 512, 0, stream>>>(O_ws, 384, WtP, bproj, (float*)d_out);
  } else {
    fused_mono<<<1024, 512, 0, stream>>>(x, mask, bproj, BIAS, WtQKV, WtP,
                                         (float*)d_out);
  }
}

// Round 7
// 446.788 us; speedup vs baseline: 2.1673x; 1.4885x over previous
//
#include <hip/hip_runtime.h>
#include <hip/hip_bf16.h>
#include <cstddef>
#include <cstdint>

// WindowAttention3D for MI355X (gfx950). Inputs f32, output f32.
// FULL path (ws >= ~265MB):
//   prep_kernel : WtQKV/WtP (bf16 transposed), BIAS, BM = bias+mask fused.
//   k_qkv       : GEMM x@Wqkv -> head-major qkv planes [h*3+seg][101376][32]
//                 (q pre-scaled), XCD-swizzled tiles.
//   k_attn      : per-window attention; contiguous per-head staging, register
//                 prefetch (next head + BM); O overwrites the dead q-plane.
//   k2_proj     : GEMM O@Wproj + b, A gathered from head-major planes.
// MID path (ws >= ~80MB): round-5 proven k1_attn + k2_proj (linear O).
// MONO path: round-4 proven monolith.

using bf16 = __hip_bfloat16;
typedef short v8s __attribute__((ext_vector_type(8)));
typedef float v4f __attribute__((ext_vector_type(4)));

static constexpr int    NTOK   = 99;
static constexpr int    CDIM   = 384;
static constexpr int    NHEAD  = 12;
static constexpr int    NROWS  = 101376;             // 1024*99
static constexpr size_t PLANE  = (size_t)NROWS * 32; // elems per head-major plane
static constexpr float  SCALEF = 0.17677669529663687f;

__device__ __forceinline__ v4f mfma16x16x32(v8s a, v8s b, v4f c) {
  return __builtin_amdgcn_mfma_f32_16x16x32_bf16(a, b, c, 0, 0, 0);
}
__device__ __forceinline__ short f2bf(float f) {
  bf16 h = __float2bfloat16(f);
  return *reinterpret_cast<short*>(&h);
}

// ---- ws layout ----
static constexpr size_t WT_QKV_OFF = 0;                          // 884,736
static constexpr size_t WT_P_OFF   = 884736;                     // 294,912
static constexpr size_t BIAS_OFF   = 884736 + 294912;            // 470,448
static constexpr size_t COMMON_END = 1650096;
// MID tier:
static constexpr size_t O_WS_OFF   = COMMON_END;
static constexpr size_t WS_MID     = O_WS_OFF + (size_t)NROWS * 384 * 2; // 79,506,864
// FULL tier:
static constexpr size_t BM_OFF     = COMMON_END;                 // 30,090,240 B
static constexpr size_t QKV_OFF    = BM_OFF + (size_t)64 * NHEAD * NTOK * NTOK * 4;
static constexpr size_t WS_FULL    = QKV_OFF + (size_t)NROWS * 1152 * 2; // 265,310,640

static constexpr int PREP_BASE = 1152 * 384 + 384 * 384 + NHEAD * 99 * 99;
static constexpr int PREP_BM   = 64 * NHEAD * 99 * 99;

// ---------------- prep ----------------
__global__ void prep_kernel(const float* __restrict__ Wqkv, const float* __restrict__ Wproj,
                            const float* __restrict__ rpb,  const int* __restrict__ rpi,
                            const float* __restrict__ mask,
                            bf16* __restrict__ WtQKV, bf16* __restrict__ WtP,
                            float* __restrict__ BIAS, float* __restrict__ BM, int do_bm)
{
  int idx = blockIdx.x * 256 + threadIdx.x;
  if (idx < 1152 * 384) {                     // WtQKV[c][k] = bf16(Wqkv[k][c])
    int c = idx / 384, k = idx - c * 384;
    WtQKV[idx] = __float2bfloat16(Wqkv[k * 1152 + c]);
  } else if (idx < 1152 * 384 + 384 * 384) {  // WtP[c][k] = bf16(Wproj[k][c])
    int j = idx - 1152 * 384;
    int c = j / 384, k = j - c * 384;
    WtP[j] = __float2bfloat16(Wproj[k * 384 + c]);
  } else if (idx < PREP_BASE) {
    int j = idx - (1152 * 384 + 384 * 384);   // BIAS[h][n][m]
    int h = j / (99 * 99), r = j - h * (99 * 99);
    int nn = r / 99, mm = r - nn * 99;
    float v = 0.f;
    if (nn > 0 && mm > 0) v = rpb[rpi[(nn - 1) * 98 + (mm - 1)] * NHEAD + h];
    BIAS[j] = v;
  } else if (do_bm && idx < PREP_BASE + PREP_BM) {
    int j = idx - PREP_BASE;                  // BM[wi][h][n][m] = bias + mask
    int wi = j / (NHEAD * 9801);
    int r2 = j - wi * (NHEAD * 9801);
    int h = r2 / 9801, rr = r2 - h * 9801;
    int nn = rr / 99, mm = rr - nn * 99;
    float v = 0.f;
    if (nn > 0 && mm > 0)
      v = rpb[rpi[(nn - 1) * 98 + (mm - 1)] * NHEAD + h]
        + mask[((size_t)wi * 98 + (nn - 1)) * 98 + (mm - 1)];
    BM[j] = v;
  }
}

// ================= k_qkv: x @ Wqkv -> head-major planes ======================
// Tiles 128x192, 512 threads, K-chunks of 64. XCD-swizzled: 4752 = 8*594.
static constexpr int GQ_LD   = 72;
static constexpr int GQ_OFFB = 0;
static constexpr int GQ_OFFA = 192 * GQ_LD * 2;
static constexpr int GQ_LDS  = GQ_OFFA + 128 * GQ_LD * 2;  // 46,080

__global__ __launch_bounds__(512)
void k_qkv(const float* __restrict__ x, const bf16* __restrict__ WtQKV,
           bf16* __restrict__ qkv2)
{
  __shared__ __align__(16) char smem[GQ_LDS];
  bf16* B_lds = (bf16*)(smem + GQ_OFFB);
  bf16* A_lds = (bf16*)(smem + GQ_OFFA);

  const int tid  = threadIdx.x;
  const int wave = tid >> 6;
  const int lane = tid & 63;
  const int g    = lane >> 4;
  const int li   = lane & 15;
  const int tile = (blockIdx.x & 7) * 594 + (blockIdx.x >> 3);  // same rows -> same XCD
  const int R0   = (tile / 6) * 128;
  const int CN   = (tile % 6) * 192;

  v4f acc[12];
  #pragma unroll
  for (int t = 0; t < 12; ++t) acc[t] = (v4f){0.f, 0.f, 0.f, 0.f};

  for (int kc = 0; kc < 6; ++kc) {
    const int k0 = kc * 64;
    #pragma unroll
    for (int p = 0; p < 3; ++p) {
      int it = tid + p * 512, rr = it >> 3, k8 = it & 7;
      *(v8s*)(B_lds + rr * GQ_LD + k8 * 8) =
          *(const v8s*)(WtQKV + (size_t)(CN + rr) * 384 + k0 + k8 * 8);
    }
    #pragma unroll
    for (int p = 0; p < 2; ++p) {
      int it = tid + p * 512, rr = it >> 3, k8 = it & 7;
      const float* src = x + (size_t)(R0 + rr) * 384 + k0 + k8 * 8;
      v4f x0 = *(const v4f*)(src);
      v4f x1 = *(const v4f*)(src + 4);
      v8s f;
      #pragma unroll
      for (int j = 0; j < 4; ++j) { f[j] = f2bf(x0[j]); f[j + 4] = f2bf(x1[j]); }
      *(v8s*)(A_lds + rr * GQ_LD + k8 * 8) = f;
    }
    __syncthreads();
    #pragma unroll
    for (int ks = 0; ks < 2; ++ks) {
      v8s ao = *(const v8s*)(A_lds + (16 * wave + li) * GQ_LD + ks * 32 + g * 8);
      #pragma unroll
      for (int t = 0; t < 12; ++t) {
        v8s bw = *(const v8s*)(B_lds + (16 * t + li) * GQ_LD + ks * 32 + g * 8);
        acc[t] = mfma16x16x32(ao, bw, acc[t]);
      }
    }
    __syncthreads();
  }

  const float scale = (CN < 384) ? SCALEF : 1.f;   // q pre-scaled
  #pragma unroll
  for (int t = 0; t < 12; ++t) {
    int col = CN + 16 * t + li;
    int seg = col / 384, within = col - seg * 384;
    int hh = within >> 5, d = within & 31;
    bf16* plane = qkv2 + (size_t)(hh * 3 + seg) * PLANE;
    #pragma unroll
    for (int j = 0; j < 4; ++j) {
      int r = R0 + 16 * wave + g * 4 + j;
      plane[(size_t)r * 32 + d] = __float2bfloat16(acc[t][j] * scale);
    }
  }
}

// ================= k_attn: per-window attention (head-major qkv) =============
static constexpr int A_QK_LD = 40;
static constexpr int A_VT_LD = 104;
static constexpr int A_P_LD  = 104;
static constexpr int A_OFF_Q = 0;
static constexpr int A_OFF_K = A_OFF_Q + 112 * A_QK_LD * 2;  //  8,960
static constexpr int A_OFF_V = A_OFF_K + 112 * A_QK_LD * 2;  // 17,920
static constexpr int A_OFF_P = A_OFF_V + 32  * A_VT_LD * 2;  // 24,576
static constexpr int A_LDS   = A_OFF_P + 112 * A_P_LD  * 2;  // 47,872

__global__ __launch_bounds__(448)
void k_attn(const float* __restrict__ BM, bf16* __restrict__ qkv2)
{
  __shared__ __align__(16) char smem[A_LDS];
  bf16* q_lds  = (bf16*)(smem + A_OFF_Q);
  bf16* k_lds  = (bf16*)(smem + A_OFF_K);
  bf16* vT_lds = (bf16*)(smem + A_OFF_V);
  bf16* P_lds  = (bf16*)(smem + A_OFF_P);

  const int b    = blockIdx.x;
  const int tid  = threadIdx.x;
  const int wave = tid >> 6;        // 0..6
  const int lane = tid & 63;
  const int g    = lane >> 4;
  const int li   = lane & 15;
  const int wi   = b & 63;

  const int r  = tid >> 2, l4 = tid & 3;       // staging coords
  const int rc = (r > 98) ? 98 : r;
  const size_t goff = ((size_t)b * NTOK + rc) * 32 + l4 * 8;  // within-plane

  // prologue: stage head 0
  {
    v8s pq = *(const v8s*)(qkv2 + 0 * PLANE + goff);
    v8s pk = *(const v8s*)(qkv2 + 1 * PLANE + goff);
    v8s pv = *(const v8s*)(qkv2 + 2 * PLANE + goff);
    *(v8s*)(q_lds + r * A_QK_LD + l4 * 8) = pq;
    *(v8s*)(k_lds + r * A_QK_LD + l4 * 8) = pk;
    if (r < NTOK) {
      #pragma unroll
      for (int e = 0; e < 8; ++e)
        *(short*)(vT_lds + (l4 * 8 + e) * A_VT_LD + r) = pv[e];
    }
  }
  __syncthreads();

  for (int h = 0; h < NHEAD; ++h) {
    // prefetch next head into registers (global latency hides under compute)
    v8s nq, nk, nv;
    if (h < NHEAD - 1) {
      nq = *(const v8s*)(qkv2 + (size_t)(h * 3 + 3) * PLANE + goff);
      nk = *(const v8s*)(qkv2 + (size_t)(h * 3 + 4) * PLANE + goff);
      nv = *(const v8s*)(qkv2 + (size_t)(h * 3 + 5) * PLANE + goff);
    }

    // prefetch BM tile into registers before the MFMAs
    const float* bm = BM + (size_t)(wi * NHEAD + h) * 9801;
    float bmr[28];
    #pragma unroll
    for (int t = 0; t < 7; ++t) {
      int col = 16 * t + li; int colc = (col > 98) ? 98 : col;
      #pragma unroll
      for (int j = 0; j < 4; ++j) {
        int row = 16 * wave + g * 4 + j; int rowc = (row > 98) ? 98 : row;
        bmr[t * 4 + j] = bm[rowc * 99 + colc];
      }
    }

    // S = q k^T
    v8s aq = *(const v8s*)(q_lds + (16 * wave + li) * A_QK_LD + g * 8);
    v4f sacc[7];
    #pragma unroll
    for (int t = 0; t < 7; ++t) {
      v8s bk = *(const v8s*)(k_lds + (16 * t + li) * A_QK_LD + g * 8);
      v4f z = (v4f){0.f, 0.f, 0.f, 0.f};
      sacc[t] = mfma16x16x32(aq, bk, z);
    }
    #pragma unroll
    for (int t = 0; t < 7; ++t) {
      int col = 16 * t + li;
      #pragma unroll
      for (int j = 0; j < 4; ++j) {
        float s = sacc[t][j];
        if (col >= NTOK) s = -1e30f;
        else             s += bmr[t * 4 + j];
        sacc[t][j] = s;
      }
    }
    // softmax (rows live in 16-lane groups)
    float linv[4];
    #pragma unroll
    for (int j = 0; j < 4; ++j) {
      float m = -1e30f;
      #pragma unroll
      for (int t = 0; t < 7; ++t) m = fmaxf(m, sacc[t][j]);
      m = fmaxf(m, __shfl_xor(m, 1));
      m = fmaxf(m, __shfl_xor(m, 2));
      m = fmaxf(m, __shfl_xor(m, 4));
      m = fmaxf(m, __shfl_xor(m, 8));
      float l = 0.f;
      #pragma unroll
      for (int t = 0; t < 7; ++t) {
        float p = __expf(sacc[t][j] - m);
        sacc[t][j] = p;
        l += p;
      }
      l += __shfl_xor(l, 1);
      l += __shfl_xor(l, 2);
      l += __shfl_xor(l, 4);
      l += __shfl_xor(l, 8);
      linv[j] = 1.f / l;
      int row = 16 * wave + g * 4 + j;
      #pragma unroll
      for (int t = 0; t < 7; ++t) {
        int col = 16 * t + li;
        if (col < NTOK) P_lds[row * A_P_LD + col] = __float2bfloat16(sacc[t][j]);
      }
    }
    // PV (MFMA over m=0..95, VALU tail m=96..98)
    v4f oacc[2];
    oacc[0] = (v4f){0.f, 0.f, 0.f, 0.f};
    oacc[1] = (v4f){0.f, 0.f, 0.f, 0.f};
    #pragma unroll
    for (int ks = 0; ks < 3; ++ks) {
      v8s ap = *(const v8s*)(P_lds + (16 * wave + li) * A_P_LD + ks * 32 + g * 8);
      #pragma unroll
      for (int t = 0; t < 2; ++t) {
        v8s bv = *(const v8s*)(vT_lds + (16 * t + li) * A_VT_LD + ks * 32 + g * 8);
        oacc[t] = mfma16x16x32(ap, bv, oacc[t]);
      }
    }
    #pragma unroll
    for (int t = 0; t < 2; ++t) {
      float v0 = __bfloat162float(vT_lds[(16 * t + li) * A_VT_LD + 96]);
      float v1 = __bfloat162float(vT_lds[(16 * t + li) * A_VT_LD + 97]);
      float v2 = __bfloat162float(vT_lds[(16 * t + li) * A_VT_LD + 98]);
      #pragma unroll
      for (int j = 0; j < 4; ++j) {
        int row = 16 * wave + g * 4 + j;
        float p0 = __bfloat162float(P_lds[row * A_P_LD + 96]);
        float p1 = __bfloat162float(P_lds[row * A_P_LD + 97]);
        float p2 = __bfloat162float(P_lds[row * A_P_LD + 98]);
        oacc[t][j] += p0 * v0 + p1 * v1 + p2 * v2;
      }
    }
    // O -> dead q-plane of head h
    bf16* oplane = qkv2 + (size_t)(h * 3) * PLANE;
    #pragma unroll
    for (int t = 0; t < 2; ++t) {
      #pragma unroll
      for (int j = 0; j < 4; ++j) {
        int row = 16 * wave + g * 4 + j;
        if (row < NTOK)
          oplane[((size_t)b * NTOK + row) * 32 + 16 * t + li] =
              __float2bfloat16(oacc[t][j] * linv[j]);
      }
    }
    __syncthreads();                 // all compute-reads of stage h done
    if (h < NHEAD - 1) {
      *(v8s*)(q_lds + r * A_QK_LD + l4 * 8) = nq;
      *(v8s*)(k_lds + r * A_QK_LD + l4 * 8) = nk;
      if (r < NTOK) {
        #pragma unroll
        for (int e = 0; e < 8; ++e)
          *(short*)(vT_lds + (l4 * 8 + e) * A_VT_LD + r) = nv[e];
      }
      __syncthreads();               // stage h+1 visible
    }
  }
}

// ================= k2_proj: out = O @ WtP^T + b, split store =================
// hm=1: A gathered from head-major q-planes; hm=0: linear [r][384].
static constexpr int K2_LD   = 72;
static constexpr int K2_OFFW = 0;
static constexpr int K2_OFFO = 192 * K2_LD * 2;
static constexpr int K2_LDS  = K2_OFFO + 128 * K2_LD * 2;   // 46,080

__global__ __launch_bounds__(512)
void k2_proj(const bf16* __restrict__ O_src, const int hm,
             const bf16* __restrict__ WtP, const float* __restrict__ bproj,
             float* __restrict__ out)
{
  __shared__ __align__(16) char smem[K2_LDS];
  bf16* W_lds = (bf16*)(smem + K2_OFFW);
  bf16* O_lds = (bf16*)(smem + K2_OFFO);

  const int tid  = threadIdx.x;
  const int wave = tid >> 6;
  const int lane = tid & 63;
  const int g    = lane >> 4;
  const int li   = lane & 15;
  const int tile = (blockIdx.x & 7) * 198 + (blockIdx.x >> 3);  // 1584 = 8*198
  const int R0   = (tile >> 1) * 128;
  const int CN   = (tile & 1) * 192;

  v4f acc[12];
  #pragma unroll
  for (int t = 0; t < 12; ++t) acc[t] = (v4f){0.f, 0.f, 0.f, 0.f};

  for (int kc = 0; kc < 6; ++kc) {
    const int k0 = kc * 64;
    #pragma unroll
    for (int p = 0; p < 3; ++p) {
      int it = tid + p * 512, rr = it >> 3, k8 = it & 7;
      *(v8s*)(W_lds + rr * K2_LD + k8 * 8) =
          *(const v8s*)(WtP + (size_t)(CN + rr) * CDIM + k0 + k8 * 8);
    }
    #pragma unroll
    for (int p = 0; p < 2; ++p) {
      int it = tid + p * 512, rr = it >> 3, k8 = it & 7;
      const bf16* src;
      if (hm) {
        int c = k0 + k8 * 8, hh = c >> 5, d = c & 31;
        src = O_src + (size_t)(hh * 3) * PLANE + (size_t)(R0 + rr) * 32 + d;
      } else {
        src = O_src + (size_t)(R0 + rr) * 384 + k0 + k8 * 8;
      }
      *(v8s*)(O_lds + rr * K2_LD + k8 * 8) = *(const v8s*)src;
    }
    __syncthreads();
    #pragma unroll
    for (int ks = 0; ks < 2; ++ks) {
      v8s ao = *(const v8s*)(O_lds + (16 * wave + li) * K2_LD + ks * 32 + g * 8);
      #pragma unroll
      for (int t = 0; t < 12; ++t) {
        v8s bw = *(const v8s*)(W_lds + (16 * t + li) * K2_LD + ks * 32 + g * 8);
        acc[t] = mfma16x16x32(ao, bw, acc[t]);
      }
    }
    __syncthreads();
  }

  const size_t OUT2 = (size_t)1024 * 98 * CDIM;
  #pragma unroll
  for (int t = 0; t < 12; ++t) {
    int col = CN + 16 * t + li;
    float bb = bproj[col];
    #pragma unroll
    for (int j = 0; j < 4; ++j) {
      int rr = R0 + 16 * wave + g * 4 + j;
      int b = rr / 99, n = rr - b * 99;
      float v = acc[t][j] + bb;
      if (n == 0) out[OUT2 + (size_t)b * CDIM + col] = v;
      else        out[((size_t)b * 98 + (n - 1)) * CDIM + col] = v;
    }
  }
}

// ================= MID tier: round-5 proven k1_attn =========================
static constexpr int QK_LD = 40;
static constexpr int VT_LD = 136;
static constexpr int P_LD  = 136;
static constexpr int WS_LD = 104;
static constexpr int K1_OFF_Q = 0;
static constexpr int K1_OFF_K = K1_OFF_Q + 112 * QK_LD * 2;
static constexpr int K1_OFF_V = K1_OFF_K + 112 * QK_LD * 2;
static constexpr int K1_OFF_P = K1_OFF_V + 32  * VT_LD * 2;
static constexpr int K1_OFF_W = K1_OFF_P + 112 * P_LD  * 2;
static constexpr int K1_LDS   = K1_OFF_W + 96 * WS_LD * 2;

__global__ __launch_bounds__(512)
void k1_attn(const float* __restrict__ x, const float* __restrict__ mask,
             const float* __restrict__ BIAS, const bf16* __restrict__ WtQKV,
             bf16* __restrict__ O_ws)
{
  __shared__ __align__(16) char smem[K1_LDS];
  bf16* q_lds  = (bf16*)(smem + K1_OFF_Q);
  bf16* k_lds  = (bf16*)(smem + K1_OFF_K);
  bf16* vT_lds = (bf16*)(smem + K1_OFF_V);
  bf16* P_lds  = (bf16*)(smem + K1_OFF_P);
  bf16* w_lds  = (bf16*)(smem + K1_OFF_W);

  const int b    = blockIdx.x;
  const int tid  = threadIdx.x;
  const int wave = tid >> 6;
  const int lane = tid & 63;
  const int g    = lane >> 4;
  const int li   = lane & 15;
  const int wi   = b & 63;

  v8s afr[12];
  if (wave < 7) {
    int arow = 16 * wave + li; if (arow > 98) arow = 98;
    const float* xb = x + ((size_t)b * NTOK + arow) * CDIM + g * 8;
    #pragma unroll
    for (int s = 0; s < 12; ++s) {
      v4f x0 = *(const v4f*)(xb + s * 32);
      v4f x1 = *(const v4f*)(xb + s * 32 + 4);
      v8s f;
      #pragma unroll
      for (int j = 0; j < 4; ++j) { f[j] = f2bf(x0[j]); f[j + 4] = f2bf(x1[j]); }
      afr[s] = f;
    }
  }

  for (int h = 0; h < NHEAD; ++h) {
    v4f qacc[6];
    #pragma unroll
    for (int t = 0; t < 6; ++t) qacc[t] = (v4f){0.f, 0.f, 0.f, 0.f};
    #pragma unroll
    for (int c4 = 0; c4 < 4; ++c4) {
      for (int idx = tid; idx < 96 * 12; idx += 512) {
        int rr = idx / 12, ch = idx - rr * 12;
        int cg = (rr < 32) ? (h * 32 + rr)
               : (rr < 64) ? (CDIM + h * 32 + rr - 32)
                           : (2 * CDIM + h * 32 + rr - 64);
        *(v8s*)(w_lds + rr * WS_LD + ch * 8) =
            *(const v8s*)(WtQKV + (size_t)cg * CDIM + c4 * 96 + ch * 8);
      }
      __syncthreads();
      if (wave < 7) {
        #pragma unroll
        for (int ss = 0; ss < 3; ++ss) {
          const int s = c4 * 3 + ss;
          #pragma unroll
          for (int t = 0; t < 6; ++t) {
            v8s bw = *(const v8s*)(w_lds + (16 * t + li) * WS_LD + ss * 32 + g * 8);
            qacc[t] = mfma16x16x32(afr[s], bw, qacc[t]);
          }
        }
      }
      __syncthreads();
    }
    if (wave < 7) {
      #pragma unroll
      for (int t = 0; t < 6; ++t) {
        #pragma unroll
        for (int j = 0; j < 4; ++j) {
          int row = 16 * wave + g * 4 + j;
          int col = 16 * (t & 1) + li;
          float v = qacc[t][j];
          if (t < 2)      q_lds[row * QK_LD + col] = __float2bfloat16(v * SCALEF);
          else if (t < 4) k_lds[row * QK_LD + col] = __float2bfloat16(v);
          else            vT_lds[col * VT_LD + row] = __float2bfloat16(v);
        }
      }
    }
    vT_lds[(tid >> 4) * VT_LD + 112 + (tid & 15)] = __float2bfloat16(0.f);
    __syncthreads();

    if (wave < 7) {
      v8s aq = *(const v8s*)(q_lds + (16 * wave + li) * QK_LD + g * 8);
      v4f sacc[7];
      #pragma unroll
      for (int t = 0; t < 7; ++t) {
        v8s bk = *(const v8s*)(k_lds + (16 * t + li) * QK_LD + g * 8);
        v4f z = (v4f){0.f, 0.f, 0.f, 0.f};
        sacc[t] = mfma16x16x32(aq, bk, z);
      }
      #pragma unroll
      for (int t = 0; t < 7; ++t) {
        int col = 16 * t + li;
        #pragma unroll
        for (int j = 0; j < 4; ++j) {
          int row = 16 * wave + g * 4 + j;
          float s = sacc[t][j];
          if (col >= NTOK) s = -1e30f;
          else if (row < NTOK) {
            s += BIAS[(h * NTOK + row) * NTOK + col];
            if (row > 0 && col > 0)
              s += mask[((size_t)wi * 98 + (row - 1)) * 98 + (col - 1)];
          }
          sacc[t][j] = s;
        }
      }
      float linv[4];
      #pragma unroll
      for (int j = 0; j < 4; ++j) {
        float m = -1e30f;
        #pragma unroll
        for (int t = 0; t < 7; ++t) m = fmaxf(m, sacc[t][j]);
        m = fmaxf(m, __shfl_xor(m, 1));
        m = fmaxf(m, __shfl_xor(m, 2));
        m = fmaxf(m, __shfl_xor(m, 4));
        m = fmaxf(m, __shfl_xor(m, 8));
        float l = 0.f;
        #pragma unroll
        for (int t = 0; t < 7; ++t) {
          float p = __expf(sacc[t][j] - m);
          sacc[t][j] = p;
          l += p;
        }
        l += __shfl_xor(l, 1);
        l += __shfl_xor(l, 2);
        l += __shfl_xor(l, 4);
        l += __shfl_xor(l, 8);
        linv[j] = 1.f / l;
        int row = 16 * wave + g * 4 + j;
        #pragma unroll
        for (int t = 0; t < 7; ++t)
          P_lds[row * P_LD + 16 * t + li] = __float2bfloat16(sacc[t][j]);
        P_lds[row * P_LD + 112 + li] = __float2bfloat16(0.f);
      }
      v4f oacc[2];
      oacc[0] = (v4f){0.f, 0.f, 0.f, 0.f};
      oacc[1] = (v4f){0.f, 0.f, 0.f, 0.f};
      #pragma unroll
      for (int ks = 0; ks < 4; ++ks) {
        v8s ap = *(const v8s*)(P_lds + (16 * wave + li) * P_LD + ks * 32 + g * 8);
        #pragma unroll
        for (int t = 0; t < 2; ++t) {
          v8s bv = *(const v8s*)(vT_lds + (16 * t + li) * VT_LD + ks * 32 + g * 8);
          oacc[t] = mfma16x16x32(ap, bv, oacc[t]);
        }
      }
      #pragma unroll
      for (int t = 0; t < 2; ++t) {
        #pragma unroll
        for (int j = 0; j < 4; ++j) {
          int row = 16 * wave + g * 4 + j;
          if (row < NTOK)
            O_ws[((size_t)b * 99 + row) * CDIM + h * 32 + 16 * t + li] =
                __float2bfloat16(oacc[t][j] * linv[j]);
        }
      }
    }
    __syncthreads();
  }
}

// ================= MONO tier: round-4 proven =================================
static constexpr int M_O_LD = 392;
static constexpr int M_OFF_O = 0;
static constexpr int M_OFF_Q = M_OFF_O + 99  * M_O_LD * 2;
static constexpr int M_OFF_K = M_OFF_Q + 112 * QK_LD * 2;
static constexpr int M_OFF_V = M_OFF_K + 112 * QK_LD * 2;
static constexpr int M_OFF_P = M_OFF_V + 32  * VT_LD * 2;
static constexpr int M_OFF_W = M_OFF_P + 112 * P_LD  * 2;
static constexpr int M_LDS   = M_OFF_W + 96 * WS_LD * 2;

__global__ __launch_bounds__(512)
void fused_mono(const float* __restrict__ x, const float* __restrict__ mask,
                const float* __restrict__ bproj, const float* __restrict__ BIAS,
                const bf16* __restrict__ WtQKV, const bf16* __restrict__ WtP,
                float* __restrict__ out)
{
  __shared__ __align__(16) char smem[M_LDS];
  bf16* O_lds  = (bf16*)(smem + M_OFF_O);
  bf16* q_lds  = (bf16*)(smem + M_OFF_Q);
  bf16* k_lds  = (bf16*)(smem + M_OFF_K);
  bf16* vT_lds = (bf16*)(smem + M_OFF_V);
  bf16* P_lds  = (bf16*)(smem + M_OFF_P);
  bf16* w_lds  = (bf16*)(smem + M_OFF_W);

  const int b    = blockIdx.x;
  const int tid  = threadIdx.x;
  const int wave = tid >> 6;
  const int lane = tid & 63;
  const int g    = lane >> 4;
  const int li   = lane & 15;
  const int wi   = b & 63;

  v8s afr[12];
  if (wave < 7) {
    int arow = 16 * wave + li; if (arow > 98) arow = 98;
    const float* xb = x + ((size_t)b * NTOK + arow) * CDIM + g * 8;
    #pragma unroll
    for (int s = 0; s < 12; ++s) {
      v4f x0 = *(const v4f*)(xb + s * 32);
      v4f x1 = *(const v4f*)(xb + s * 32 + 4);
      v8s f;
      #pragma unroll
      for (int j = 0; j < 4; ++j) { f[j] = f2bf(x0[j]); f[j + 4] = f2bf(x1[j]); }
      afr[s] = f;
    }
  }

  for (int h = 0; h < NHEAD; ++h) {
    v4f qacc[6];
    #pragma unroll
    for (int t = 0; t < 6; ++t) qacc[t] = (v4f){0.f, 0.f, 0.f, 0.f};
    #pragma unroll
    for (int c4 = 0; c4 < 4; ++c4) {
      for (int idx = tid; idx < 96 * 12; idx += 512) {
        int rr = idx / 12, ch = idx - rr * 12;
        int cg = (rr < 32) ? (h * 32 + rr)
               : (rr < 64) ? (CDIM + h * 32 + rr - 32)
                           : (2 * CDIM + h * 32 + rr - 64);
        *(v8s*)(w_lds + rr * WS_LD + ch * 8) =
            *(const v8s*)(WtQKV + (size_t)cg * CDIM + c4 * 96 + ch * 8);
      }
      __syncthreads();
      if (wave < 7) {
        #pragma unroll
        for (int ss = 0; ss < 3; ++ss) {
          const int s = c4 * 3 + ss;
          #pragma unroll
          for (int t = 0; t < 6; ++t) {
            v8s bw = *(const v8s*)(w_lds + (16 * t + li) * WS_LD + ss * 32 + g * 8);
            qacc[t] = mfma16x16x32(afr[s], bw, qacc[t]);
          }
        }
      }
      __syncthreads();
    }
    if (wave < 7) {
      #pragma unroll
      for (int t = 0; t < 6; ++t) {
        #pragma unroll
        for (int j = 0; j < 4; ++j) {
          int row = 16 * wave + g * 4 + j;
          int col = 16 * (t & 1) + li;
          float v = qacc[t][j];
          if (t < 2)      q_lds[row * QK_LD + col] = __float2bfloat16(v * SCALEF);
          else if (t < 4) k_lds[row * QK_LD + col] = __float2bfloat16(v);
          else            vT_lds[col * VT_LD + row] = __float2bfloat16(v);
        }
      }
    }
    vT_lds[(tid >> 4) * VT_LD + 112 + (tid & 15)] = __float2bfloat16(0.f);
    __syncthreads();

    if (wave < 7) {
      v8s aq = *(const v8s*)(q_lds + (16 * wave + li) * QK_LD + g * 8);
      v4f sacc[7];
      #pragma unroll
      for (int t = 0; t < 7; ++t) {
        v8s bk = *(const v8s*)(k_lds + (16 * t + li) * QK_LD + g * 8);
        v4f z = (v4f){0.f, 0.f, 0.f, 0.f};
        sacc[t] = mfma16x16x32(aq, bk, z);
      }
      #pragma unroll
      for (int t = 0; t < 7; ++t) {
        int col = 16 * t + li;
        #pragma unroll
        for (int j = 0; j < 4; ++j) {
          int row = 16 * wave + g * 4 + j;
          float s = sacc[t][j];
          if (col >= NTOK) s = -1e30f;
          else if (row < NTOK) {
            s += BIAS[(h * NTOK + row) * NTOK + col];
            if (row > 0 && col > 0)
              s += mask[((size_t)wi * 98 + (row - 1)) * 98 + (col - 1)];
          }
          sacc[t][j] = s;
        }
      }
      float linv[4];
      #pragma unroll
      for (int j = 0; j < 4; ++j) {
        float m = -1e30f;
        #pragma unroll
        for (int t = 0; t < 7; ++t) m = fmaxf(m, sacc[t][j]);
        m = fmaxf(m, __shfl_xor(m, 1));
        m = fmaxf(m, __shfl_xor(m, 2));
        m = fmaxf(m, __shfl_xor(m, 4));
        m = fmaxf(m, __shfl_xor(m, 8));
        float l = 0.f;
        #pragma unroll
        for (int t = 0; t < 7; ++t) {
          float p = __expf(sacc[t][j] - m);
          sacc[t][j] = p;
          l += p;
        }
        l += __shfl_xor(l, 1);
        l += __shfl_xor(l, 2);
        l += __shfl_xor(l, 4);
        l += __shfl_xor(l, 8);
        linv[j] = 1.f / l;
        int row = 16 * wave + g * 4 + j;
        #pragma unroll
        for (int t = 0; t < 7; ++t)
          P_lds[row * P_LD + 16 * t + li] = __float2bfloat16(sacc[t][j]);
        P_lds[row * P_LD + 112 + li] = __float2bfloat16(0.f);
      }
      v4f oacc[2];
      oacc[0] = (v4f){0.f, 0.f, 0.f, 0.f};
      oacc[1] = (v4f){0.f, 0.f, 0.f, 0.f};
      #pragma unroll
      for (int ks = 0; ks < 4; ++ks) {
        v8s ap = *(const v8s*)(P_lds + (16 * wave + li) * P_LD + ks * 32 + g * 8);
        #pragma unroll
        for (int t = 0; t < 2; ++t) {
          v8s bv = *(const v8s*)(vT_lds + (16 * t + li) * VT_LD + ks * 32 + g * 8);
          oacc[t] = mfma16x16x32(ap, bv, oacc[t]);
        }
      }
      #pragma unroll
      for (int t = 0; t < 2; ++t) {
        #pragma unroll
        for (int j = 0; j < 4; ++j) {
          int row = 16 * wave + g * 4 + j;
          if (row < NTOK)
            O_lds[row * M_O_LD + h * 32 + 16 * t + li] =
                __float2bfloat16(oacc[t][j] * linv[j]);
        }
      }
    }
    __syncthreads();
  }

  const size_t OUT2 = (size_t)1024 * 98 * CDIM;
  const int orow_clamped = (16 * wave + li > 98) ? 98 : 16 * wave + li;
  for (int cc = 0; cc < 4; ++cc) {
    v4f pacc[6];
    #pragma unroll
    for (int t = 0; t < 6; ++t) pacc[t] = (v4f){0.f, 0.f, 0.f, 0.f};
    for (int c4 = 0; c4 < 4; ++c4) {
      for (int idx = tid; idx < 96 * 12; idx += 512) {
        int rr = idx / 12, ch = idx - rr * 12;
        *(v8s*)(w_lds + rr * WS_LD + ch * 8) =
            *(const v8s*)(WtP + ((size_t)(cc * 96 + rr)) * CDIM + c4 * 96 + ch * 8);
      }
      __syncthreads();
      if (wave < 7) {
        #pragma unroll
        for (int ss = 0; ss < 3; ++ss) {
          const int s = c4 * 3 + ss;
          v8s ao = *(const v8s*)(O_lds + orow_clamped * M_O_LD + s * 32 + g * 8);
          #pragma unroll
          for (int t = 0; t < 6; ++t) {
            v8s bw = *(const v8s*)(w_lds + (16 * t + li) * WS_LD + ss * 32 + g * 8);
            pacc[t] = mfma16x16x32(ao, bw, pacc[t]);
          }
        }
      }
      __syncthreads();
    }
    if (wave < 7) {
      #pragma unroll
      for (int t = 0; t < 6; ++t) {
        #pragma unroll
        for (int j = 0; j < 4; ++j) {
          int row = 16 * wave + g * 4 + j;
          if (row < NTOK) {
            int col = cc * 96 + 16 * t + li;
            float v = pacc[t][j] + bproj[col];
            if (row == 0) out[OUT2 + (size_t)b * CDIM + col] = v;
            else          out[((size_t)b * 98 + (row - 1)) * CDIM + col] = v;
          }
        }
      }
    }
  }
}

extern "C" void kernel_launch(void* const* d_in, const int* in_sizes, int n_in,
                              void* d_out, int out_size, void* d_ws, size_t ws_size,
                              hipStream_t stream) {
  const float* x     = (const float*)d_in[0];
  const float* mask  = (const float*)d_in[1];
  const float* Wqkv  = (const float*)d_in[2];
  const float* rpb   = (const float*)d_in[3];
  const float* Wproj = (const float*)d_in[4];
  const float* bproj = (const float*)d_in[5];
  const int*   rpi   = (const int*)d_in[6];

  bf16*  WtQKV = (bf16*)((char*)d_ws + WT_QKV_OFF);
  bf16*  WtP   = (bf16*)((char*)d_ws + WT_P_OFF);
  float* BIAS  = (float*)((char*)d_ws + BIAS_OFF);

  const bool full = (ws_size >= WS_FULL);
  const int prep_items = full ? (PREP_BASE + PREP_BM) : PREP_BASE;
  float* BM = (float*)((char*)d_ws + BM_OFF);
  prep_kernel<<<(prep_items + 255) / 256, 256, 0, stream>>>(
      Wqkv, Wproj, rpb, rpi, mask, WtQKV, WtP, BIAS, BM, full ? 1 : 0);

  if (full) {
    bf16* qkv2 = (bf16*)((char*)d_ws + QKV_OFF);
    k_qkv<<<792 * 6, 512, 0, stream>>>(x, WtQKV, qkv2);
    k_attn<<<1024, 448, 0, stream>>>(BM, qkv2);
    k2_proj<<<792 * 2, 512, 0, stream>>>(qkv2, 1, WtP, bproj, (float*)d_out);
  } else if (ws_size >= WS_MID) {
    bf16* O_ws = (bf16*)((char*)d_ws + O_WS_OFF);
    k1_attn<<<1024, 512, 0, stream>>>(x, mask, BIAS, WtQKV, O_ws);
    k2_proj<<<792 * 2, 512, 0, stream>>>(O_ws, 0, WtP, bproj, (float*)d_out);
  } else {
    fused_mono<<<1024, 512, 0, stream>>>(x, mask, bproj, BIAS, WtQKV, WtP,
                                         (float*)d_out);
  }
}

// Round 8
// 425.717 us; speedup vs baseline: 2.2745x; 1.0495x over previous
//
#include <hip/hip_runtime.h>
#include <hip/hip_bf16.h>
#include <cstddef>
#include <cstdint>

// WindowAttention3D for MI355X (gfx950). Inputs f32, output f32.
// FULL path (ws >= ~265MB):
//   prep_kernel : WtQKV/WtP (bf16 transposed), BIAS, BM = bias+mask fused.
//   k_qkv       : GEMM x@Wqkv -> head-major qkv planes; 2x4 wave decomposition,
//                 LDS-staged coalesced epilogue, XCD-swizzled tiles.
//   k_attn      : per-window attention, 2 blocks/window (6 heads each);
//                 contiguous staging + register prefetch; O -> dead q-plane.
//   k2_proj     : GEMM O@Wproj + b, 2x4 wave decomposition.
// MID path (ws >= ~80MB): round-5 proven k1_attn + k2_proj (linear O).
// MONO path: round-4 proven monolith.

using bf16 = __hip_bfloat16;
typedef short v8s __attribute__((ext_vector_type(8)));
typedef float v4f __attribute__((ext_vector_type(4)));

static constexpr int    NTOK   = 99;
static constexpr int    CDIM   = 384;
static constexpr int    NHEAD  = 12;
static constexpr int    NROWS  = 101376;             // 1024*99
static constexpr size_t PLANE  = (size_t)NROWS * 32; // elems per head-major plane
static constexpr float  SCALEF = 0.17677669529663687f;

__device__ __forceinline__ v4f mfma16x16x32(v8s a, v8s b, v4f c) {
  return __builtin_amdgcn_mfma_f32_16x16x32_bf16(a, b, c, 0, 0, 0);
}
__device__ __forceinline__ short f2bf(float f) {
  bf16 h = __float2bfloat16(f);
  return *reinterpret_cast<short*>(&h);
}

// ---- ws layout ----
static constexpr size_t WT_QKV_OFF = 0;                          // 884,736
static constexpr size_t WT_P_OFF   = 884736;                     // 294,912
static constexpr size_t BIAS_OFF   = 884736 + 294912;            // 470,448
static constexpr size_t COMMON_END = 1650096;
// MID tier:
static constexpr size_t O_WS_OFF   = COMMON_END;
static constexpr size_t WS_MID     = O_WS_OFF + (size_t)NROWS * 384 * 2; // 79,506,864
// FULL tier:
static constexpr size_t BM_OFF     = COMMON_END;                 // 30,090,240 B
static constexpr size_t QKV_OFF    = BM_OFF + (size_t)64 * NHEAD * NTOK * NTOK * 4;
static constexpr size_t WS_FULL    = QKV_OFF + (size_t)NROWS * 1152 * 2; // 265,310,640

static constexpr int PREP_BASE = 1152 * 384 + 384 * 384 + NHEAD * 99 * 99;
static constexpr int PREP_BM   = 64 * NHEAD * 99 * 99;

// ---------------- prep ----------------
__global__ void prep_kernel(const float* __restrict__ Wqkv, const float* __restrict__ Wproj,
                            const float* __restrict__ rpb,  const int* __restrict__ rpi,
                            const float* __restrict__ mask,
                            bf16* __restrict__ WtQKV, bf16* __restrict__ WtP,
                            float* __restrict__ BIAS, float* __restrict__ BM, int do_bm)
{
  int idx = blockIdx.x * 256 + threadIdx.x;
  if (idx < 1152 * 384) {                     // WtQKV[c][k] = bf16(Wqkv[k][c])
    int c = idx / 384, k = idx - c * 384;
    WtQKV[idx] = __float2bfloat16(Wqkv[k * 1152 + c]);
  } else if (idx < 1152 * 384 + 384 * 384) {  // WtP[c][k] = bf16(Wproj[k][c])
    int j = idx - 1152 * 384;
    int c = j / 384, k = j - c * 384;
    WtP[j] = __float2bfloat16(Wproj[k * 384 + c]);
  } else if (idx < PREP_BASE) {
    int j = idx - (1152 * 384 + 384 * 384);   // BIAS[h][n][m]
    int h = j / (99 * 99), r = j - h * (99 * 99);
    int nn = r / 99, mm = r - nn * 99;
    float v = 0.f;
    if (nn > 0 && mm > 0) v = rpb[rpi[(nn - 1) * 98 + (mm - 1)] * NHEAD + h];
    BIAS[j] = v;
  } else if (do_bm && idx < PREP_BASE + PREP_BM) {
    int j = idx - PREP_BASE;                  // BM[wi][h][n][m] = bias + mask
    int wi = j / (NHEAD * 9801);
    int r2 = j - wi * (NHEAD * 9801);
    int h = r2 / 9801, rr = r2 - h * 9801;
    int nn = rr / 99, mm = rr - nn * 99;
    float v = 0.f;
    if (nn > 0 && mm > 0)
      v = rpb[rpi[(nn - 1) * 98 + (mm - 1)] * NHEAD + h]
        + mask[((size_t)wi * 98 + (nn - 1)) * 98 + (mm - 1)];
    BM[j] = v;
  }
}

// ================= k_qkv: x @ Wqkv -> head-major planes ======================
// Tiles 128x192, 512 threads (waves 2x4: 64 rows x 48 cols each), K-chunks 64.
static constexpr int GQ_LD    = 72;
static constexpr int GQ_OFFB  = 0;
static constexpr int GQ_OFFA  = 192 * GQ_LD * 2;
static constexpr int GQ_LDS   = GQ_OFFA + 128 * GQ_LD * 2;  // 46,080
static constexpr int CSTG_LD  = 104;                        // 128 x 104 x 2 = 26,624

__global__ __launch_bounds__(512)
void k_qkv(const float* __restrict__ x, const bf16* __restrict__ WtQKV,
           bf16* __restrict__ qkv2)
{
  __shared__ __align__(16) char smem[GQ_LDS];
  bf16* B_lds = (bf16*)(smem + GQ_OFFB);
  bf16* A_lds = (bf16*)(smem + GQ_OFFA);
  bf16* C_stg = (bf16*)(smem);                 // reused after K loop

  const int tid  = threadIdx.x;
  const int wave = tid >> 6;
  const int wm   = wave >> 2;                  // 0..1 (row band of 64)
  const int wn   = wave & 3;                   // 0..3 (col band of 48)
  const int lane = tid & 63;
  const int g    = lane >> 4;
  const int li   = lane & 15;
  const int tile = (blockIdx.x & 7) * 594 + (blockIdx.x >> 3);  // 4752 = 8*594
  const int R0   = (tile / 6) * 128;
  const int CN   = (tile % 6) * 192;

  v4f acc[4][3];
  #pragma unroll
  for (int mi = 0; mi < 4; ++mi)
    #pragma unroll
    for (int ni = 0; ni < 3; ++ni) acc[mi][ni] = (v4f){0.f, 0.f, 0.f, 0.f};

  for (int kc = 0; kc < 6; ++kc) {
    const int k0 = kc * 64;
    #pragma unroll
    for (int p = 0; p < 3; ++p) {              // stage B: 192 x 64
      int it = tid + p * 512, rr = it >> 3, k8 = it & 7;
      *(v8s*)(B_lds + rr * GQ_LD + k8 * 8) =
          *(const v8s*)(WtQKV + (size_t)(CN + rr) * 384 + k0 + k8 * 8);
    }
    #pragma unroll
    for (int p = 0; p < 2; ++p) {              // stage A: 128 x 64, f32->bf16
      int it = tid + p * 512, rr = it >> 3, k8 = it & 7;
      const float* src = x + (size_t)(R0 + rr) * 384 + k0 + k8 * 8;
      v4f x0 = *(const v4f*)(src);
      v4f x1 = *(const v4f*)(src + 4);
      v8s f;
      #pragma unroll
      for (int j = 0; j < 4; ++j) { f[j] = f2bf(x0[j]); f[j + 4] = f2bf(x1[j]); }
      *(v8s*)(A_lds + rr * GQ_LD + k8 * 8) = f;
    }
    __syncthreads();
    #pragma unroll
    for (int ks = 0; ks < 2; ++ks) {
      v8s af[4], bfr[3];
      #pragma unroll
      for (int mi = 0; mi < 4; ++mi)
        af[mi] = *(const v8s*)(A_lds + (wm * 64 + mi * 16 + li) * GQ_LD + ks * 32 + g * 8);
      #pragma unroll
      for (int ni = 0; ni < 3; ++ni)
        bfr[ni] = *(const v8s*)(B_lds + (wn * 48 + ni * 16 + li) * GQ_LD + ks * 32 + g * 8);
      #pragma unroll
      for (int mi = 0; mi < 4; ++mi)
        #pragma unroll
        for (int ni = 0; ni < 3; ++ni)
          acc[mi][ni] = mfma16x16x32(af[mi], bfr[ni], acc[mi][ni]);
    }
    __syncthreads();
  }

  // ---- epilogue: LDS-staged, coalesced v8s stores to head-major planes ----
  const float scale = (CN < 384) ? SCALEF : 1.f;   // q tiles pre-scaled
  const int r_ep = tid >> 2, d8 = tid & 3;
  #pragma unroll
  for (int half = 0; half < 2; ++half) {
    __syncthreads();
    if ((wn >> 1) == half) {
      #pragma unroll
      for (int mi = 0; mi < 4; ++mi)
        #pragma unroll
        for (int ni = 0; ni < 3; ++ni)
          #pragma unroll
          for (int j = 0; j < 4; ++j)
            C_stg[(wm * 64 + mi * 16 + g * 4 + j) * CSTG_LD + (wn & 1) * 48 + ni * 16 + li] =
                __float2bfloat16(acc[mi][ni][j] * scale);
    }
    __syncthreads();
    #pragma unroll
    for (int cidx = 0; cidx < 3; ++cidx) {
      int c_global = CN + half * 96 + cidx * 32;
      int seg = c_global / 384, hh = (c_global % 384) >> 5;
      bf16* plane = qkv2 + (size_t)(hh * 3 + seg) * PLANE;
      v8s val = *(const v8s*)(C_stg + r_ep * CSTG_LD + cidx * 32 + d8 * 8);
      *(v8s*)(plane + (size_t)(R0 + r_ep) * 32 + d8 * 8) = val;
    }
  }
}

// ================= k_attn: per-window attention (head-major qkv) =============
// grid (1024, 2): block y handles heads [6y, 6y+6).
static constexpr int A_QK_LD = 40;
static constexpr int A_VT_LD = 104;
static constexpr int A_P_LD  = 104;
static constexpr int A_OFF_Q = 0;
static constexpr int A_OFF_K = A_OFF_Q + 112 * A_QK_LD * 2;  //  8,960
static constexpr int A_OFF_V = A_OFF_K + 112 * A_QK_LD * 2;  // 17,920
static constexpr int A_OFF_P = A_OFF_V + 32  * A_VT_LD * 2;  // 24,576
static constexpr int A_LDS   = A_OFF_P + 112 * A_P_LD  * 2;  // 47,872

__global__ __launch_bounds__(448)
void k_attn(const float* __restrict__ BM, bf16* __restrict__ qkv2)
{
  __shared__ __align__(16) char smem[A_LDS];
  bf16* q_lds  = (bf16*)(smem + A_OFF_Q);
  bf16* k_lds  = (bf16*)(smem + A_OFF_K);
  bf16* vT_lds = (bf16*)(smem + A_OFF_V);
  bf16* P_lds  = (bf16*)(smem + A_OFF_P);

  const int b    = blockIdx.x;
  const int h0   = blockIdx.y * 6;
  const int tid  = threadIdx.x;
  const int wave = tid >> 6;        // 0..6
  const int lane = tid & 63;
  const int g    = lane >> 4;
  const int li   = lane & 15;
  const int wi   = b & 63;

  const int r  = tid >> 2, l4 = tid & 3;       // staging coords
  const int rc = (r > 98) ? 98 : r;
  const size_t goff = ((size_t)b * NTOK + rc) * 32 + l4 * 8;  // within-plane

  // prologue: stage head h0
  {
    v8s pq = *(const v8s*)(qkv2 + (size_t)(h0 * 3 + 0) * PLANE + goff);
    v8s pk = *(const v8s*)(qkv2 + (size_t)(h0 * 3 + 1) * PLANE + goff);
    v8s pv = *(const v8s*)(qkv2 + (size_t)(h0 * 3 + 2) * PLANE + goff);
    *(v8s*)(q_lds + r * A_QK_LD + l4 * 8) = pq;
    *(v8s*)(k_lds + r * A_QK_LD + l4 * 8) = pk;
    if (r < NTOK) {
      #pragma unroll
      for (int e = 0; e < 8; ++e)
        *(short*)(vT_lds + (l4 * 8 + e) * A_VT_LD + r) = pv[e];
    }
  }
  __syncthreads();

  for (int hi = 0; hi < 6; ++hi) {
    const int h = h0 + hi;
    // prefetch next head into registers (global latency hides under compute)
    v8s nq, nk, nv;
    if (hi < 5) {
      nq = *(const v8s*)(qkv2 + (size_t)(h * 3 + 3) * PLANE + goff);
      nk = *(const v8s*)(qkv2 + (size_t)(h * 3 + 4) * PLANE + goff);
      nv = *(const v8s*)(qkv2 + (size_t)(h * 3 + 5) * PLANE + goff);
    }

    // prefetch BM tile into registers before the MFMAs
    const float* bm = BM + (size_t)(wi * NHEAD + h) * 9801;
    float bmr[28];
    #pragma unroll
    for (int t = 0; t < 7; ++t) {
      int col = 16 * t + li; int colc = (col > 98) ? 98 : col;
      #pragma unroll
      for (int j = 0; j < 4; ++j) {
        int row = 16 * wave + g * 4 + j; int rowc = (row > 98) ? 98 : row;
        bmr[t * 4 + j] = bm[rowc * 99 + colc];
      }
    }

    // S = q k^T
    v8s aq = *(const v8s*)(q_lds + (16 * wave + li) * A_QK_LD + g * 8);
    v4f sacc[7];
    #pragma unroll
    for (int t = 0; t < 7; ++t) {
      v8s bk = *(const v8s*)(k_lds + (16 * t + li) * A_QK_LD + g * 8);
      v4f z = (v4f){0.f, 0.f, 0.f, 0.f};
      sacc[t] = mfma16x16x32(aq, bk, z);
    }
    #pragma unroll
    for (int t = 0; t < 7; ++t) {
      int col = 16 * t + li;
      #pragma unroll
      for (int j = 0; j < 4; ++j) {
        float s = sacc[t][j];
        if (col >= NTOK) s = -1e30f;
        else             s += bmr[t * 4 + j];
        sacc[t][j] = s;
      }
    }
    // softmax (rows live in 16-lane groups)
    float linv[4];
    #pragma unroll
    for (int j = 0; j < 4; ++j) {
      float m = -1e30f;
      #pragma unroll
      for (int t = 0; t < 7; ++t) m = fmaxf(m, sacc[t][j]);
      m = fmaxf(m, __shfl_xor(m, 1));
      m = fmaxf(m, __shfl_xor(m, 2));
      m = fmaxf(m, __shfl_xor(m, 4));
      m = fmaxf(m, __shfl_xor(m, 8));
      float l = 0.f;
      #pragma unroll
      for (int t = 0; t < 7; ++t) {
        float p = __expf(sacc[t][j] - m);
        sacc[t][j] = p;
        l += p;
      }
      l += __shfl_xor(l, 1);
      l += __shfl_xor(l, 2);
      l += __shfl_xor(l, 4);
      l += __shfl_xor(l, 8);
      linv[j] = 1.f / l;
      int row = 16 * wave + g * 4 + j;
      #pragma unroll
      for (int t = 0; t < 7; ++t) {
        int col = 16 * t + li;
        if (col < NTOK) P_lds[row * A_P_LD + col] = __float2bfloat16(sacc[t][j]);
      }
    }
    // PV (MFMA over m=0..95, VALU tail m=96..98)
    v4f oacc[2];
    oacc[0] = (v4f){0.f, 0.f, 0.f, 0.f};
    oacc[1] = (v4f){0.f, 0.f, 0.f, 0.f};
    #pragma unroll
    for (int ks = 0; ks < 3; ++ks) {
      v8s ap = *(const v8s*)(P_lds + (16 * wave + li) * A_P_LD + ks * 32 + g * 8);
      #pragma unroll
      for (int t = 0; t < 2; ++t) {
        v8s bv = *(const v8s*)(vT_lds + (16 * t + li) * A_VT_LD + ks * 32 + g * 8);
        oacc[t] = mfma16x16x32(ap, bv, oacc[t]);
      }
    }
    #pragma unroll
    for (int t = 0; t < 2; ++t) {
      float v0 = __bfloat162float(vT_lds[(16 * t + li) * A_VT_LD + 96]);
      float v1 = __bfloat162float(vT_lds[(16 * t + li) * A_VT_LD + 97]);
      float v2 = __bfloat162float(vT_lds[(16 * t + li) * A_VT_LD + 98]);
      #pragma unroll
      for (int j = 0; j < 4; ++j) {
        int row = 16 * wave + g * 4 + j;
        float p0 = __bfloat162float(P_lds[row * A_P_LD + 96]);
        float p1 = __bfloat162float(P_lds[row * A_P_LD + 97]);
        float p2 = __bfloat162float(P_lds[row * A_P_LD + 98]);
        oacc[t][j] += p0 * v0 + p1 * v1 + p2 * v2;
      }
    }
    // O -> dead q-plane of head h
    bf16* oplane = qkv2 + (size_t)(h * 3) * PLANE;
    #pragma unroll
    for (int t = 0; t < 2; ++t) {
      #pragma unroll
      for (int j = 0; j < 4; ++j) {
        int row = 16 * wave + g * 4 + j;
        if (row < NTOK)
          oplane[((size_t)b * NTOK + row) * 32 + 16 * t + li] =
              __float2bfloat16(oacc[t][j] * linv[j]);
      }
    }
    __syncthreads();                 // all compute-reads of stage h done
    if (hi < 5) {
      *(v8s*)(q_lds + r * A_QK_LD + l4 * 8) = nq;
      *(v8s*)(k_lds + r * A_QK_LD + l4 * 8) = nk;
      if (r < NTOK) {
        #pragma unroll
        for (int e = 0; e < 8; ++e)
          *(short*)(vT_lds + (l4 * 8 + e) * A_VT_LD + r) = nv[e];
      }
      __syncthreads();               // stage h+1 visible
    }
  }
}

// ================= k2_proj: out = O @ WtP^T + b, split store =================
// hm=1: A gathered from head-major q-planes; hm=0: linear [r][384].
static constexpr int K2_LD   = 72;
static constexpr int K2_OFFW = 0;
static constexpr int K2_OFFO = 192 * K2_LD * 2;
static constexpr int K2_LDS  = K2_OFFO + 128 * K2_LD * 2;   // 46,080

__global__ __launch_bounds__(512)
void k2_proj(const bf16* __restrict__ O_src, const int hm,
             const bf16* __restrict__ WtP, const float* __restrict__ bproj,
             float* __restrict__ out)
{
  __shared__ __align__(16) char smem[K2_LDS];
  bf16* W_lds = (bf16*)(smem + K2_OFFW);
  bf16* O_lds = (bf16*)(smem + K2_OFFO);

  const int tid  = threadIdx.x;
  const int wave = tid >> 6;
  const int wm   = wave >> 2;
  const int wn   = wave & 3;
  const int lane = tid & 63;
  const int g    = lane >> 4;
  const int li   = lane & 15;
  const int tile = (blockIdx.x & 7) * 198 + (blockIdx.x >> 3);  // 1584 = 8*198
  const int R0   = (tile >> 1) * 128;
  const int CN   = (tile & 1) * 192;

  v4f acc[4][3];
  #pragma unroll
  for (int mi = 0; mi < 4; ++mi)
    #pragma unroll
    for (int ni = 0; ni < 3; ++ni) acc[mi][ni] = (v4f){0.f, 0.f, 0.f, 0.f};

  for (int kc = 0; kc < 6; ++kc) {
    const int k0 = kc * 64;
    #pragma unroll
    for (int p = 0; p < 3; ++p) {
      int it = tid + p * 512, rr = it >> 3, k8 = it & 7;
      *(v8s*)(W_lds + rr * K2_LD + k8 * 8) =
          *(const v8s*)(WtP + (size_t)(CN + rr) * CDIM + k0 + k8 * 8);
    }
    #pragma unroll
    for (int p = 0; p < 2; ++p) {
      int it = tid + p * 512, rr = it >> 3, k8 = it & 7;
      const bf16* src;
      if (hm) {
        int c = k0 + k8 * 8, hh = c >> 5, d = c & 31;
        src = O_src + (size_t)(hh * 3) * PLANE + (size_t)(R0 + rr) * 32 + d;
      } else {
        src = O_src + (size_t)(R0 + rr) * 384 + k0 + k8 * 8;
      }
      *(v8s*)(O_lds + rr * K2_LD + k8 * 8) = *(const v8s*)src;
    }
    __syncthreads();
    #pragma unroll
    for (int ks = 0; ks < 2; ++ks) {
      v8s af[4], bfr[3];
      #pragma unroll
      for (int mi = 0; mi < 4; ++mi)
        af[mi] = *(const v8s*)(O_lds + (wm * 64 + mi * 16 + li) * K2_LD + ks * 32 + g * 8);
      #pragma unroll
      for (int ni = 0; ni < 3; ++ni)
        bfr[ni] = *(const v8s*)(W_lds + (wn * 48 + ni * 16 + li) * K2_LD + ks * 32 + g * 8);
      #pragma unroll
      for (int mi = 0; mi < 4; ++mi)
        #pragma unroll
        for (int ni = 0; ni < 3; ++ni)
          acc[mi][ni] = mfma16x16x32(af[mi], bfr[ni], acc[mi][ni]);
    }
    __syncthreads();
  }

  const size_t OUT2 = (size_t)1024 * 98 * CDIM;
  #pragma unroll
  for (int mi = 0; mi < 4; ++mi)
    #pragma unroll
    for (int ni = 0; ni < 3; ++ni) {
      int col = CN + wn * 48 + ni * 16 + li;
      float bb = bproj[col];
      #pragma unroll
      for (int j = 0; j < 4; ++j) {
        int rr = R0 + wm * 64 + mi * 16 + g * 4 + j;
        int b = rr / 99, n = rr - b * 99;
        float v = acc[mi][ni][j] + bb;
        if (n == 0) out[OUT2 + (size_t)b * CDIM + col] = v;
        else        out[((size_t)b * 98 + (n - 1)) * CDIM + col] = v;
      }
    }
}

// ================= MID tier: round-5 proven k1_attn =========================
static constexpr int QK_LD = 40;
static constexpr int VT_LD = 136;
static constexpr int P_LD  = 136;
static constexpr int WS_LD = 104;
static constexpr int K1_OFF_Q = 0;
static constexpr int K1_OFF_K = K1_OFF_Q + 112 * QK_LD * 2;
static constexpr int K1_OFF_V = K1_OFF_K + 112 * QK_LD * 2;
static constexpr int K1_OFF_P = K1_OFF_V + 32  * VT_LD * 2;
static constexpr int K1_OFF_W = K1_OFF_P + 112 * P_LD  * 2;
static constexpr int K1_LDS   = K1_OFF_W + 96 * WS_LD * 2;

__global__ __launch_bounds__(512)
void k1_attn(const float* __restrict__ x, const float* __restrict__ mask,
             const float* __restrict__ BIAS, const bf16* __restrict__ WtQKV,
             bf16* __restrict__ O_ws)
{
  __shared__ __align__(16) char smem[K1_LDS];
  bf16* q_lds  = (bf16*)(smem + K1_OFF_Q);
  bf16* k_lds  = (bf16*)(smem + K1_OFF_K);
  bf16* vT_lds = (bf16*)(smem + K1_OFF_V);
  bf16* P_lds  = (bf16*)(smem + K1_OFF_P);
  bf16* w_lds  = (bf16*)(smem + K1_OFF_W);

  const int b    = blockIdx.x;
  const int tid  = threadIdx.x;
  const int wave = tid >> 6;
  const int lane = tid & 63;
  const int g    = lane >> 4;
  const int li   = lane & 15;
  const int wi   = b & 63;

  v8s afr[12];
  if (wave < 7) {
    int arow = 16 * wave + li; if (arow > 98) arow = 98;
    const float* xb = x + ((size_t)b * NTOK + arow) * CDIM + g * 8;
    #pragma unroll
    for (int s = 0; s < 12; ++s) {
      v4f x0 = *(const v4f*)(xb + s * 32);
      v4f x1 = *(const v4f*)(xb + s * 32 + 4);
      v8s f;
      #pragma unroll
      for (int j = 0; j < 4; ++j) { f[j] = f2bf(x0[j]); f[j + 4] = f2bf(x1[j]); }
      afr[s] = f;
    }
  }

  for (int h = 0; h < NHEAD; ++h) {
    v4f qacc[6];
    #pragma unroll
    for (int t = 0; t < 6; ++t) qacc[t] = (v4f){0.f, 0.f, 0.f, 0.f};
    #pragma unroll
    for (int c4 = 0; c4 < 4; ++c4) {
      for (int idx = tid; idx < 96 * 12; idx += 512) {
        int rr = idx / 12, ch = idx - rr * 12;
        int cg = (rr < 32) ? (h * 32 + rr)
               : (rr < 64) ? (CDIM + h * 32 + rr - 32)
                           : (2 * CDIM + h * 32 + rr - 64);
        *(v8s*)(w_lds + rr * WS_LD + ch * 8) =
            *(const v8s*)(WtQKV + (size_t)cg * CDIM + c4 * 96 + ch * 8);
      }
      __syncthreads();
      if (wave < 7) {
        #pragma unroll
        for (int ss = 0; ss < 3; ++ss) {
          const int s = c4 * 3 + ss;
          #pragma unroll
          for (int t = 0; t < 6; ++t) {
            v8s bw = *(const v8s*)(w_lds + (16 * t + li) * WS_LD + ss * 32 + g * 8);
            qacc[t] = mfma16x16x32(afr[s], bw, qacc[t]);
          }
        }
      }
      __syncthreads();
    }
    if (wave < 7) {
      #pragma unroll
      for (int t = 0; t < 6; ++t) {
        #pragma unroll
        for (int j = 0; j < 4; ++j) {
          int row = 16 * wave + g * 4 + j;
          int col = 16 * (t & 1) + li;
          float v = qacc[t][j];
          if (t < 2)      q_lds[row * QK_LD + col] = __float2bfloat16(v * SCALEF);
          else if (t < 4) k_lds[row * QK_LD + col] = __float2bfloat16(v);
          else            vT_lds[col * VT_LD + row] = __float2bfloat16(v);
        }
      }
    }
    vT_lds[(tid >> 4) * VT_LD + 112 + (tid & 15)] = __float2bfloat16(0.f);
    __syncthreads();

    if (wave < 7) {
      v8s aq = *(const v8s*)(q_lds + (16 * wave + li) * QK_LD + g * 8);
      v4f sacc[7];
      #pragma unroll
      for (int t = 0; t < 7; ++t) {
        v8s bk = *(const v8s*)(k_lds + (16 * t + li) * QK_LD + g * 8);
        v4f z = (v4f){0.f, 0.f, 0.f, 0.f};
        sacc[t] = mfma16x16x32(aq, bk, z);
      }
      #pragma unroll
      for (int t = 0; t < 7; ++t) {
        int col = 16 * t + li;
        #pragma unroll
        for (int j = 0; j < 4; ++j) {
          int row = 16 * wave + g * 4 + j;
          float s = sacc[t][j];
          if (col >= NTOK) s = -1e30f;
          else if (row < NTOK) {
            s += BIAS[(h * NTOK + row) * NTOK + col];
            if (row > 0 && col > 0)
              s += mask[((size_t)wi * 98 + (row - 1)) * 98 + (col - 1)];
          }
          sacc[t][j] = s;
        }
      }
      float linv[4];
      #pragma unroll
      for (int j = 0; j < 4; ++j) {
        float m = -1e30f;
        #pragma unroll
        for (int t = 0; t < 7; ++t) m = fmaxf(m, sacc[t][j]);
        m = fmaxf(m, __shfl_xor(m, 1));
        m = fmaxf(m, __shfl_xor(m, 2));
        m = fmaxf(m, __shfl_xor(m, 4));
        m = fmaxf(m, __shfl_xor(m, 8));
        float l = 0.f;
        #pragma unroll
        for (int t = 0; t < 7; ++t) {
          float p = __expf(sacc[t][j] - m);
          sacc[t][j] = p;
          l += p;
        }
        l += __shfl_xor(l, 1);
        l += __shfl_xor(l, 2);
        l += __shfl_xor(l, 4);
        l += __shfl_xor(l, 8);
        linv[j] = 1.f / l;
        int row = 16 * wave + g * 4 + j;
        #pragma unroll
        for (int t = 0; t < 7; ++t)
          P_lds[row * P_LD + 16 * t + li] = __float2bfloat16(sacc[t][j]);
        P_lds[row * P_LD + 112 + li] = __float2bfloat16(0.f);
      }
      v4f oacc[2];
      oacc[0] = (v4f){0.f, 0.f, 0.f, 0.f};
      oacc[1] = (v4f){0.f, 0.f, 0.f, 0.f};
      #pragma unroll
      for (int ks = 0; ks < 4; ++ks) {
        v8s ap = *(const v8s*)(P_lds + (16 * wave + li) * P_LD + ks * 32 + g * 8);
        #pragma unroll
        for (int t = 0; t < 2; ++t) {
          v8s bv = *(const v8s*)(vT_lds + (16 * t + li) * VT_LD + ks * 32 + g * 8);
          oacc[t] = mfma16x16x32(ap, bv, oacc[t]);
        }
      }
      #pragma unroll
      for (int t = 0; t < 2; ++t) {
        #pragma unroll
        for (int j = 0; j < 4; ++j) {
          int row = 16 * wave + g * 4 + j;
          if (row < NTOK)
            O_ws[((size_t)b * 99 + row) * CDIM + h * 32 + 16 * t + li] =
                __float2bfloat16(oacc[t][j] * linv[j]);
        }
      }
    }
    __syncthreads();
  }
}

// ================= MONO tier: round-4 proven =================================
static constexpr int M_O_LD = 392;
static constexpr int M_OFF_O = 0;
static constexpr int M_OFF_Q = M_OFF_O + 99  * M_O_LD * 2;
static constexpr int M_OFF_K = M_OFF_Q + 112 * QK_LD * 2;
static constexpr int M_OFF_V = M_OFF_K + 112 * QK_LD * 2;
static constexpr int M_OFF_P = M_OFF_V + 32  * VT_LD * 2;
static constexpr int M_OFF_W = M_OFF_P + 112 * P_LD  * 2;
static constexpr int M_LDS   = M_OFF_W + 96 * WS_LD * 2;

__global__ __launch_bounds__(512)
void fused_mono(const float* __restrict__ x, const float* __restrict__ mask,
                const float* __restrict__ bproj, const float* __restrict__ BIAS,
                const bf16* __restrict__ WtQKV, const bf16* __restrict__ WtP,
                float* __restrict__ out)
{
  __shared__ __align__(16) char smem[M_LDS];
  bf16* O_lds  = (bf16*)(smem + M_OFF_O);
  bf16* q_lds  = (bf16*)(smem + M_OFF_Q);
  bf16* k_lds  = (bf16*)(smem + M_OFF_K);
  bf16* vT_lds = (bf16*)(smem + M_OFF_V);
  bf16* P_lds  = (bf16*)(smem + M_OFF_P);
  bf16* w_lds  = (bf16*)(smem + M_OFF_W);

  const int b    = blockIdx.x;
  const int tid  = threadIdx.x;
  const int wave = tid >> 6;
  const int lane = tid & 63;
  const int g    = lane >> 4;
  const int li   = lane & 15;
  const int wi   = b & 63;

  v8s afr[12];
  if (wave < 7) {
    int arow = 16 * wave + li; if (arow > 98) arow = 98;
    const float* xb = x + ((size_t)b * NTOK + arow) * CDIM + g * 8;
    #pragma unroll
    for (int s = 0; s < 12; ++s) {
      v4f x0 = *(const v4f*)(xb + s * 32);
      v4f x1 = *(const v4f*)(xb + s * 32 + 4);
      v8s f;
      #pragma unroll
      for (int j = 0; j < 4; ++j) { f[j] = f2bf(x0[j]); f[j + 4] = f2bf(x1[j]); }
      afr[s] = f;
    }
  }

  for (int h = 0; h < NHEAD; ++h) {
    v4f qacc[6];
    #pragma unroll
    for (int t = 0; t < 6; ++t) qacc[t] = (v4f){0.f, 0.f, 0.f, 0.f};
    #pragma unroll
    for (int c4 = 0; c4 < 4; ++c4) {
      for (int idx = tid; idx < 96 * 12; idx += 512) {
        int rr = idx / 12, ch = idx - rr * 12;
        int cg = (rr < 32) ? (h * 32 + rr)
               : (rr < 64) ? (CDIM + h * 32 + rr - 32)
                           : (2 * CDIM + h * 32 + rr - 64);
        *(v8s*)(w_lds + rr * WS_LD + ch * 8) =
            *(const v8s*)(WtQKV + (size_t)cg * CDIM + c4 * 96 + ch * 8);
      }
      __syncthreads();
      if (wave < 7) {
        #pragma unroll
        for (int ss = 0; ss < 3; ++ss) {
          const int s = c4 * 3 + ss;
          #pragma unroll
          for (int t = 0; t < 6; ++t) {
            v8s bw = *(const v8s*)(w_lds + (16 * t + li) * WS_LD + ss * 32 + g * 8);
            qacc[t] = mfma16x16x32(afr[s], bw, qacc[t]);
          }
        }
      }
      __syncthreads();
    }
    if (wave < 7) {
      #pragma unroll
      for (int t = 0; t < 6; ++t) {
        #pragma unroll
        for (int j = 0; j < 4; ++j) {
          int row = 16 * wave + g * 4 + j;
          int col = 16 * (t & 1) + li;
          float v = qacc[t][j];
          if (t < 2)      q_lds[row * QK_LD + col] = __float2bfloat16(v * SCALEF);
          else if (t < 4) k_lds[row * QK_LD + col] = __float2bfloat16(v);
          else            vT_lds[col * VT_LD + row] = __float2bfloat16(v);
        }
      }
    }
    vT_lds[(tid >> 4) * VT_LD + 112 + (tid & 15)] = __float2bfloat16(0.f);
    __syncthreads();

    if (wave < 7) {
      v8s aq = *(const v8s*)(q_lds + (16 * wave + li) * QK_LD + g * 8);
      v4f sacc[7];
      #pragma unroll
      for (int t = 0; t < 7; ++t) {
        v8s bk = *(const v8s*)(k_lds + (16 * t + li) * QK_LD + g * 8);
        v4f z = (v4f){0.f, 0.f, 0.f, 0.f};
        sacc[t] = mfma16x16x32(aq, bk, z);
      }
      #pragma unroll
      for (int t = 0; t < 7; ++t) {
        int col = 16 * t + li;
        #pragma unroll
        for (int j = 0; j < 4; ++j) {
          int row = 16 * wave + g * 4 + j;
          float s = sacc[t][j];
          if (col >= NTOK) s = -1e30f;
          else if (row < NTOK) {
            s += BIAS[(h * NTOK + row) * NTOK + col];
            if (row > 0 && col > 0)
              s += mask[((size_t)wi * 98 + (row - 1)) * 98 + (col - 1)];
          }
          sacc[t][j] = s;
        }
      }
      float linv[4];
      #pragma unroll
      for (int j = 0; j < 4; ++j) {
        float m = -1e30f;
        #pragma unroll
        for (int t = 0; t < 7; ++t) m = fmaxf(m, sacc[t][j]);
        m = fmaxf(m, __shfl_xor(m, 1));
        m = fmaxf(m, __shfl_xor(m, 2));
        m = fmaxf(m, __shfl_xor(m, 4));
        m = fmaxf(m, __shfl_xor(m, 8));
        float l = 0.f;
        #pragma unroll
        for (int t = 0; t < 7; ++t) {
          float p = __expf(sacc[t][j] - m);
          sacc[t][j] = p;
          l += p;
        }
        l += __shfl_xor(l, 1);
        l += __shfl_xor(l, 2);
        l += __shfl_xor(l, 4);
        l += __shfl_xor(l, 8);
        linv[j] = 1.f / l;
        int row = 16 * wave + g * 4 + j;
        #pragma unroll
        for (int t = 0; t < 7; ++t)
          P_lds[row * P_LD + 16 * t + li] = __float2bfloat16(sacc[t][j]);
        P_lds[row * P_LD + 112 + li] = __float2bfloat16(0.f);
      }
      v4f oacc[2];
      oacc[0] = (v4f){0.f, 0.f, 0.f, 0.f};
      oacc[1] = (v4f){0.f, 0.f, 0.f, 0.f};
      #pragma unroll
      for (int ks = 0; ks < 4; ++ks) {
        v8s ap = *(const v8s*)(P_lds + (16 * wave + li) * P_LD + ks * 32 + g * 8);
        #pragma unroll
        for (int t = 0; t < 2; ++t) {
          v8s bv = *(const v8s*)(vT_lds + (16 * t + li) * VT_LD + ks * 32 + g * 8);
          oacc[t] = mfma16x16x32(ap, bv, oacc[t]);
        }
      }
      #pragma unroll
      for (int t = 0; t < 2; ++t) {
        #pragma unroll
        for (int j = 0; j < 4; ++j) {
          int row = 16 * wave + g * 4 + j;
          if (row < NTOK)
            O_lds[row * M_O_LD + h * 32 + 16 * t + li] =
                __float2bfloat16(oacc[t][j] * linv[j]);
        }
      }
    }
    __syncthreads();
  }

  const size_t OUT2 = (size_t)1024 * 98 * CDIM;
  const int orow_clamped = (16 * wave + li > 98) ? 98 : 16 * wave + li;
  for (int cc = 0; cc < 4; ++cc) {
    v4f pacc[6];
    #pragma unroll
    for (int t = 0; t < 6; ++t) pacc[t] = (v4f){0.f, 0.f, 0.f, 0.f};
    for (int c4 = 0; c4 < 4; ++c4) {
      for (int idx = tid; idx < 96 * 12; idx += 512) {
        int rr = idx / 12, ch = idx - rr * 12;
        *(v8s*)(w_lds + rr * WS_LD + ch * 8) =
            *(const v8s*)(WtP + ((size_t)(cc * 96 + rr)) * CDIM + c4 * 96 + ch * 8);
      }
      __syncthreads();
      if (wave < 7) {
        #pragma unroll
        for (int ss = 0; ss < 3; ++ss) {
          const int s = c4 * 3 + ss;
          v8s ao = *(const v8s*)(O_lds + orow_clamped * M_O_LD + s * 32 + g * 8);
          #pragma unroll
          for (int t = 0; t < 6; ++t) {
            v8s bw = *(const v8s*)(w_lds + (16 * t + li) * WS_LD + ss * 32 + g * 8);
            pacc[t] = mfma16x16x32(ao, bw, pacc[t]);
          }
        }
      }
      __syncthreads();
    }
    if (wave < 7) {
      #pragma unroll
      for (int t = 0; t < 6; ++t) {
        #pragma unroll
        for (int j = 0; j < 4; ++j) {
          int row = 16 * wave + g * 4 + j;
          if (row < NTOK) {
            int col = cc * 96 + 16 * t + li;
            float v = pacc[t][j] + bproj[col];
            if (row == 0) out[OUT2 + (size_t)b * CDIM + col] = v;
            else          out[((size_t)b * 98 + (row - 1)) * CDIM + col] = v;
          }
        }
      }
    }
  }
}

extern "C" void kernel_launch(void* const* d_in, const int* in_sizes, int n_in,
                              void* d_out, int out_size, void* d_ws, size_t ws_size,
                              hipStream_t stream) {
  const float* x     = (const float*)d_in[0];
  const float* mask  = (const float*)d_in[1];
  const float* Wqkv  = (const float*)d_in[2];
  const float* rpb   = (const float*)d_in[3];
  const float* Wproj = (const float*)d_in[4];
  const float* bproj = (const float*)d_in[5];
  const int*   rpi   = (const int*)d_in[6];

  bf16*  WtQKV = (bf16*)((char*)d_ws + WT_QKV_OFF);
  bf16*  WtP   = (bf16*)((char*)d_ws + WT_P_OFF);
  float* BIAS  = (float*)((char*)d_ws + BIAS_OFF);

  const bool full = (ws_size >= WS_FULL);
  const int prep_items = full ? (PREP_BASE + PREP_BM) : PREP_BASE;
  float* BM = (float*)((char*)d_ws + BM_OFF);
  prep_kernel<<<(prep_items + 255) / 256, 256, 0, stream>>>(
      Wqkv, Wproj, rpb, rpi, mask, WtQKV, WtP, BIAS, BM, full ? 1 : 0);

  if (full) {
    bf16* qkv2 = (bf16*)((char*)d_ws + QKV_OFF);
    k_qkv<<<792 * 6, 512, 0, stream>>>(x, WtQKV, qkv2);
    k_attn<<<dim3(1024, 2), 448, 0, stream>>>(BM, qkv2);
    k2_proj<<<792 * 2, 512, 0, stream>>>(qkv2, 1, WtP, bproj, (float*)d_out);
  } else if (ws_size >= WS_MID) {
    bf16* O_ws = (bf16*)((char*)d_ws + O_WS_OFF);
    k1_attn<<<1024, 512, 0, stream>>>(x, mask, BIAS, WtQKV, O_ws);
    k2_proj<<<792 * 2, 512, 0, stream>>>(O_ws, 0, WtP, bproj, (float*)d_out);
  } else {
    fused_mono<<<1024, 512, 0, stream>>>(x, mask, bproj, BIAS, WtQKV, WtP,
                                         (float*)d_out);
  }
}